// Round 1
// baseline (1798.078 us; speedup 1.0000x reference)
//
#include <hip/hip_runtime.h>
#include <hip/hip_bf16.h>

#define H_ 2048
#define E_ 64
#define I_ 768
#define K_ 8

// ---------------- Router: logits -> softmax -> top-8 -> renormalize ----------
__global__ __launch_bounds__(256) void router_kernel(
    const float* __restrict__ x, const float* __restrict__ gw,
    int* __restrict__ topk_id, float* __restrict__ topk_w) {
  __shared__ float xs[H_];
  __shared__ float probs[E_];
  int m = blockIdx.x;
  const float* xr = x + (size_t)m * H_;
  for (int i = threadIdx.x; i < H_; i += 256) xs[i] = xr[i];
  __syncthreads();
  // 4 threads per expert
  int e = threadIdx.x >> 2, part = threadIdx.x & 3;
  const float* gr = gw + (size_t)e * H_ + part * (H_ / 4);
  const float* xx = xs + part * (H_ / 4);
  float s = 0.f;
#pragma unroll 8
  for (int i = 0; i < H_ / 4; ++i) s = fmaf(xx[i], gr[i], s);
  s += __shfl_xor(s, 1);
  s += __shfl_xor(s, 2);
  if (part == 0) probs[e] = s;
  __syncthreads();
  if (threadIdx.x == 0) {
    float mx = -1e30f;
    for (int i = 0; i < E_; ++i) mx = fmaxf(mx, probs[i]);
    float sum = 0.f;
    for (int i = 0; i < E_; ++i) { float p = expf(probs[i] - mx); probs[i] = p; sum += p; }
    float inv = 1.f / sum;
    for (int i = 0; i < E_; ++i) probs[i] *= inv;
    float bw[K_]; int bi[K_]; float wsum = 0.f;
#pragma unroll
    for (int k = 0; k < K_; ++k) {
      float best = -1.f; int b = 0;
      for (int i = 0; i < E_; ++i) if (probs[i] > best) { best = probs[i]; b = i; }
      bw[k] = best; bi[k] = b; wsum += best; probs[b] = -2.f;
    }
    float winv = 1.f / wsum;
#pragma unroll
    for (int k = 0; k < K_; ++k) {
      topk_id[m * K_ + k] = bi[k];
      topk_w[m * K_ + k] = bw[k] * winv;
    }
  }
}

// ---------------- Expert list build ----------------
__global__ void zero_cnt_kernel(int* cnt) {
  if (threadIdx.x < E_) cnt[threadIdx.x] = 0;
}

__global__ void scatter_kernel(const int* __restrict__ topk_id, int* cnt,
                               int* perEx, int MK, int M) {
  int idx = blockIdx.x * 256 + threadIdx.x;
  if (idx >= MK) return;
  int e = topk_id[idx];
  int pos = atomicAdd(cnt + e, 1);
  perEx[e * M + pos] = idx;  // idx == m*K_+k
}

__global__ void scan_kernel(const int* cnt, int* off) {
  if (threadIdx.x == 0) {
    int a = 0;
    for (int e = 0; e < E_; ++e) { off[e] = a; a += cnt[e]; }
    off[E_] = a;
  }
}

__global__ void compact_kernel(const int* __restrict__ cnt, const int* __restrict__ off,
                               const int* __restrict__ perEx,
                               int* __restrict__ entry_mk, int* __restrict__ slot2g, int M) {
  int e = blockIdx.x; int n = cnt[e]; int b = off[e];
  for (int p = threadIdx.x; p < n; p += 256) {
    int mk = perEx[e * M + p];
    entry_mk[b + p] = mk;
    slot2g[mk] = b + p;
  }
}

// ---------------- Gate/Up GEMM + SiLU: ACT[g, i] ----------------
// Per block: expert e, token tile of 64, i tile of 32 (gate+up both).
__global__ __launch_bounds__(256) void gateup_kernel(
    const float* __restrict__ x, const float* __restrict__ w13,
    const int* __restrict__ cnt, const int* __restrict__ off,
    const int* __restrict__ entry_mk, float* __restrict__ ACT) {
  int e = blockIdx.z, tt = blockIdx.y, it = blockIdx.x;
  int ne = cnt[e];
  int t0 = tt * 64;
  if (t0 >= ne) return;
  int base = off[e];
  int i0 = it * 32;

  __shared__ float Xs[64][33];
  __shared__ float Wg[32][33];
  __shared__ float Wu[32][33];
  __shared__ int toks[64];

  int tid = threadIdx.x;
  if (tid < 64) {
    int p = t0 + tid;
    toks[tid] = (p < ne) ? (entry_mk[base + p] >> 3) : -1;
  }
  __syncthreads();

  float accg[4][2] = {{0.f}}, accu[4][2] = {{0.f}};
  const float* w13e = w13 + (size_t)e * 2 * I_ * H_;
  int tr = tid >> 4, tc = tid & 15;

  for (int h0 = 0; h0 < H_; h0 += 32) {
    // stage X tile: 64x32
#pragma unroll
    for (int l = 0; l < 8; ++l) {
      int idx = tid + l * 256;
      int r = idx >> 5, c = idx & 31;
      int tk = toks[r];
      Xs[r][c] = (tk >= 0) ? x[(size_t)tk * H_ + h0 + c] : 0.f;
    }
    // stage Wg/Wu tiles: 32x32 each
#pragma unroll
    for (int l = 0; l < 4; ++l) {
      int idx = tid + l * 256;
      int r = idx >> 5, c = idx & 31;
      Wg[r][c] = w13e[(size_t)(i0 + r) * H_ + h0 + c];
      Wu[r][c] = w13e[(size_t)(i0 + r + I_) * H_ + h0 + c];
    }
    __syncthreads();
#pragma unroll
    for (int kk = 0; kk < 32; ++kk) {
      float xv[4], gg[2], uu[2];
#pragma unroll
      for (int a = 0; a < 4; ++a) xv[a] = Xs[tr * 4 + a][kk];
#pragma unroll
      for (int b = 0; b < 2; ++b) { gg[b] = Wg[tc * 2 + b][kk]; uu[b] = Wu[tc * 2 + b][kk]; }
#pragma unroll
      for (int a = 0; a < 4; ++a)
#pragma unroll
        for (int b = 0; b < 2; ++b) {
          accg[a][b] = fmaf(xv[a], gg[b], accg[a][b]);
          accu[a][b] = fmaf(xv[a], uu[b], accu[a][b]);
        }
    }
    __syncthreads();
  }

#pragma unroll
  for (int a = 0; a < 4; ++a) {
    int p = t0 + tr * 4 + a;
    if (p >= ne) continue;
    int g = base + p;
#pragma unroll
    for (int b = 0; b < 2; ++b) {
      float gv = accg[a][b], uv = accu[a][b];
      float act = gv / (1.f + __expf(-gv)) * uv;
      ACT[(size_t)g * I_ + i0 + tc * 2 + b] = act;
    }
  }
}

// ---------------- Down GEMM: OUTS[g, h] ----------------
// Per block: expert e, token tile of 64, h tile of 64.
__global__ __launch_bounds__(256) void down_kernel(
    const float* __restrict__ ACT, const float* __restrict__ w2,
    const int* __restrict__ cnt, const int* __restrict__ off,
    float* __restrict__ OUTS) {
  int e = blockIdx.z, tt = blockIdx.y, ht = blockIdx.x;
  int ne = cnt[e]; int t0 = tt * 64;
  if (t0 >= ne) return;
  int base = off[e];
  int h0 = ht * 64;

  __shared__ float As[64][33];
  __shared__ float Ws[64][33];
  int tid = threadIdx.x;
  float acc[4][4] = {{0.f}};
  const float* w2e = w2 + (size_t)e * H_ * I_;
  int tr = tid >> 4, tc = tid & 15;

  for (int i0 = 0; i0 < I_; i0 += 32) {
#pragma unroll
    for (int l = 0; l < 8; ++l) {
      int idx = tid + l * 256;
      int r = idx >> 5, c = idx & 31;
      int p = t0 + r;
      As[r][c] = (p < ne) ? ACT[(size_t)(base + p) * I_ + i0 + c] : 0.f;
      Ws[r][c] = w2e[(size_t)(h0 + r) * I_ + i0 + c];
    }
    __syncthreads();
#pragma unroll
    for (int kk = 0; kk < 32; ++kk) {
      float av[4], wv[4];
#pragma unroll
      for (int a = 0; a < 4; ++a) av[a] = As[tr * 4 + a][kk];
#pragma unroll
      for (int b = 0; b < 4; ++b) wv[b] = Ws[tc * 4 + b][kk];
#pragma unroll
      for (int a = 0; a < 4; ++a)
#pragma unroll
        for (int b = 0; b < 4; ++b) acc[a][b] = fmaf(av[a], wv[b], acc[a][b]);
    }
    __syncthreads();
  }

#pragma unroll
  for (int a = 0; a < 4; ++a) {
    int p = t0 + tr * 4 + a;
    if (p >= ne) continue;
    float* o = OUTS + (size_t)(base + p) * H_ + h0 + tc * 4;
#pragma unroll
    for (int b = 0; b < 4; ++b) o[b] = acc[a][b];
  }
}

// ---------------- Weighted combine ----------------
__global__ __launch_bounds__(256) void combine_kernel(
    const float* __restrict__ OUTS, const float* __restrict__ topk_w,
    const int* __restrict__ slot2g, float* __restrict__ out) {
  int m = blockIdx.x;
  float w[K_]; int g[K_];
#pragma unroll
  for (int k = 0; k < K_; ++k) { w[k] = topk_w[m * K_ + k]; g[k] = slot2g[m * K_ + k]; }
  for (int h = threadIdx.x; h < H_; h += 256) {
    float s = 0.f;
#pragma unroll
    for (int k = 0; k < K_; ++k) s = fmaf(w[k], OUTS[(size_t)g[k] * H_ + h], s);
    out[(size_t)m * H_ + h] = s;
  }
}

extern "C" void kernel_launch(void* const* d_in, const int* in_sizes, int n_in,
                              void* d_out, int out_size, void* d_ws, size_t ws_size,
                              hipStream_t stream) {
  const float* x   = (const float*)d_in[0];
  const float* gw  = (const float*)d_in[1];
  const float* w13 = (const float*)d_in[2];
  const float* w2  = (const float*)d_in[3];
  float* out = (float*)d_out;

  const int M = in_sizes[0] / H_;   // 512
  const int MK = M * K_;            // 4096

  char* ws = (char*)d_ws;
  size_t o = 0;
  auto alloc = [&](size_t bytes) { size_t r = o; o = (o + bytes + 255) & ~(size_t)255; return r; };
  int*   topk_id  = (int*)(ws + alloc((size_t)MK * 4));
  float* topk_w   = (float*)(ws + alloc((size_t)MK * 4));
  int*   cnt      = (int*)(ws + alloc(E_ * 4));
  int*   off      = (int*)(ws + alloc((E_ + 1) * 4));
  int*   perEx    = (int*)(ws + alloc((size_t)E_ * M * 4));
  int*   entry_mk = (int*)(ws + alloc((size_t)MK * 4));
  int*   slot2g   = (int*)(ws + alloc((size_t)MK * 4));
  float* ACT      = (float*)(ws + alloc((size_t)MK * I_ * 4));
  float* OUTS     = (float*)(ws + alloc((size_t)MK * H_ * 4));
  (void)ws_size; (void)n_in; (void)out_size;

  router_kernel<<<M, 256, 0, stream>>>(x, gw, topk_id, topk_w);
  zero_cnt_kernel<<<1, 256, 0, stream>>>(cnt);
  scatter_kernel<<<(MK + 255) / 256, 256, 0, stream>>>(topk_id, cnt, perEx, MK, M);
  scan_kernel<<<1, 64, 0, stream>>>(cnt, off);
  compact_kernel<<<E_, 256, 0, stream>>>(cnt, off, perEx, entry_mk, slot2g, M);
  gateup_kernel<<<dim3(I_ / 32, (M + 63) / 64, E_), 256, 0, stream>>>(
      x, w13, cnt, off, entry_mk, ACT);
  down_kernel<<<dim3(H_ / 64, (M + 63) / 64, E_), 256, 0, stream>>>(
      ACT, w2, cnt, off, OUTS);
  combine_kernel<<<M, 256, 0, stream>>>(OUTS, topk_w, slot2g, out);
}

// Round 2
// 646.001 us; speedup vs baseline: 2.7834x; 2.7834x over previous
//
#include <hip/hip_runtime.h>
#include <hip/hip_bf16.h>

#define H_ 2048
#define E_ 64
#define I_ 768
#define K_ 8
#define MAXT 8

typedef __attribute__((ext_vector_type(8))) __bf16 bf16x8;
typedef __attribute__((ext_vector_type(4))) float f32x4;

__device__ inline unsigned short f2bfbits(float f) {
  unsigned u = __float_as_uint(f);
  u = (u + 0x7fffu + ((u >> 16) & 1u)) >> 16;   // RNE
  return (unsigned short)u;
}
__device__ inline __bf16 f2bf(float f) {
  union { unsigned short s; __bf16 b; } cv; cv.s = f2bfbits(f); return cv.b;
}
__device__ inline f32x4 mfma16(bf16x8 a, bf16x8 b, f32x4 c) {
  return __builtin_amdgcn_mfma_f32_16x16x32_bf16(a, b, c, 0, 0, 0);
}
__device__ inline bf16x8 pack8(float4 a, float4 b) {
  bf16x8 r;
  r[0] = f2bf(a.x); r[1] = f2bf(a.y); r[2] = f2bf(a.z); r[3] = f2bf(a.w);
  r[4] = f2bf(b.x); r[5] = f2bf(b.y); r[6] = f2bf(b.z); r[7] = f2bf(b.w);
  return r;
}

// ---------------- Router (unchanged from R1, fp32-exact) ----------------
__global__ __launch_bounds__(256) void router_kernel(
    const float* __restrict__ x, const float* __restrict__ gw,
    int* __restrict__ topk_id, float* __restrict__ topk_w) {
  __shared__ float xs[H_];
  __shared__ float probs[E_];
  int m = blockIdx.x;
  const float* xr = x + (size_t)m * H_;
  for (int i = threadIdx.x; i < H_; i += 256) xs[i] = xr[i];
  __syncthreads();
  int e = threadIdx.x >> 2, part = threadIdx.x & 3;
  const float* gr = gw + (size_t)e * H_ + part * (H_ / 4);
  const float* xx = xs + part * (H_ / 4);
  float s = 0.f;
#pragma unroll 8
  for (int i = 0; i < H_ / 4; ++i) s = fmaf(xx[i], gr[i], s);
  s += __shfl_xor(s, 1);
  s += __shfl_xor(s, 2);
  if (part == 0) probs[e] = s;
  __syncthreads();
  if (threadIdx.x == 0) {
    float mx = -1e30f;
    for (int i = 0; i < E_; ++i) mx = fmaxf(mx, probs[i]);
    float sum = 0.f;
    for (int i = 0; i < E_; ++i) { float p = expf(probs[i] - mx); probs[i] = p; sum += p; }
    float inv = 1.f / sum;
    for (int i = 0; i < E_; ++i) probs[i] *= inv;
    float bw[K_]; int bi[K_]; float wsum = 0.f;
#pragma unroll
    for (int k = 0; k < K_; ++k) {
      float best = -1.f; int b = 0;
      for (int i = 0; i < E_; ++i) if (probs[i] > best) { best = probs[i]; b = i; }
      bw[k] = best; bi[k] = b; wsum += best; probs[b] = -2.f;
    }
    float winv = 1.f / wsum;
#pragma unroll
    for (int k = 0; k < K_; ++k) {
      topk_id[m * K_ + k] = bi[k];
      topk_w[m * K_ + k] = bw[k] * winv;
    }
  }
}

// ---------------- Expert list build ----------------
__global__ void zero_cnt_kernel(int* cnt) {
  if (threadIdx.x < E_) cnt[threadIdx.x] = 0;
}

__global__ void scatter_kernel(const int* __restrict__ topk_id, int* cnt,
                               int* perEx, int MK, int M) {
  int idx = blockIdx.x * 256 + threadIdx.x;
  if (idx >= MK) return;
  int e = topk_id[idx];
  int pos = atomicAdd(cnt + e, 1);
  perEx[e * M + pos] = idx;  // idx == m*K_+k
}

__global__ void scan_kernel(const int* cnt, int* off) {
  if (threadIdx.x == 0) {
    int a = 0;
    for (int e = 0; e < E_; ++e) { off[e] = a; a += cnt[e]; }
    off[E_] = a;
  }
}

__global__ void compact_kernel(const int* __restrict__ cnt, const int* __restrict__ off,
                               const int* __restrict__ perEx,
                               int* __restrict__ entry_mk, int* __restrict__ slot2g, int M) {
  int e = blockIdx.x; int n = cnt[e]; int b = off[e];
  for (int p = threadIdx.x; p < n; p += 256) {
    int mk = perEx[e * M + p];
    entry_mk[b + p] = mk;
    slot2g[mk] = b + p;
  }
}

// ---------------- x -> bf16 ----------------
__global__ __launch_bounds__(256) void cast_x_kernel(
    const float* __restrict__ x, __hip_bfloat16* __restrict__ xb, int n4) {
  int i = blockIdx.x * 256 + threadIdx.x;
  if (i >= n4) return;
  float4 v = reinterpret_cast<const float4*>(x)[i];
  short4 s;
  s.x = (short)f2bfbits(v.x); s.y = (short)f2bfbits(v.y);
  s.z = (short)f2bfbits(v.z); s.w = (short)f2bfbits(v.w);
  reinterpret_cast<short4*>(xb)[i] = s;
}

// ---------------- Gate/Up MFMA GEMM + SiLU -> ACT (bf16) ----------------
// Wave tile: 16 i-cols (gate AND up) x up-to-128 tokens, K=H streamed.
// No LDS: A/B fragments loaded straight from global (weights cast fp32->bf16 in reg).
__global__ __launch_bounds__(256) void gateup_mfma(
    const __hip_bfloat16* __restrict__ xb, const float* __restrict__ w13,
    const int* __restrict__ cnt, const int* __restrict__ off,
    const int* __restrict__ entry_mk, __hip_bfloat16* __restrict__ ACT) {
  int e = blockIdx.y;
  int ne = cnt[e];
  if (ne == 0) return;
  int base = off[e];
  int wv = threadIdx.x >> 6, lane = threadIdx.x & 63;
  int i0 = blockIdx.x * 64 + wv * 16;
  int col = lane & 15, kq = lane >> 4;

  const float* wg0 = w13 + (size_t)e * (2 * I_) * H_ + (size_t)(i0 + col) * H_ + kq * 8;
  const float* wu0 = wg0 + (size_t)I_ * H_;

  int ntile = (ne + 15) >> 4;
  for (int tb = 0; tb < ntile; tb += MAXT) {
    int nt = ntile - tb; if (nt > MAXT) nt = MAXT;
    const __hip_bfloat16* arow[MAXT];
#pragma unroll
    for (int t = 0; t < MAXT; ++t) {
      int p = (tb + t) * 16 + col;
      int pc = p < ne ? p : ne - 1;
      int tok = entry_mk[base + pc] >> 3;
      arow[t] = xb + (size_t)tok * H_ + kq * 8;
    }
    f32x4 accg[MAXT], accu[MAXT];
#pragma unroll
    for (int t = 0; t < MAXT; ++t) {
      accg[t] = (f32x4){0.f, 0.f, 0.f, 0.f};
      accu[t] = (f32x4){0.f, 0.f, 0.f, 0.f};
    }
    const float* wg = wg0;
    const float* wu = wu0;
    for (int k = 0; k < H_; k += 32) {
      float4 g0 = *reinterpret_cast<const float4*>(wg);
      float4 g1 = *reinterpret_cast<const float4*>(wg + 4);
      float4 u0 = *reinterpret_cast<const float4*>(wu);
      float4 u1 = *reinterpret_cast<const float4*>(wu + 4);
      bf16x8 bg = pack8(g0, g1);
      bf16x8 bu = pack8(u0, u1);
#pragma unroll
      for (int t = 0; t < MAXT; ++t) {
        if (t < nt) {
          bf16x8 a = *reinterpret_cast<const bf16x8*>(arow[t]);
          accg[t] = mfma16(a, bg, accg[t]);
          accu[t] = mfma16(a, bu, accu[t]);
          arow[t] += 32;
        }
      }
      wg += 32; wu += 32;
    }
    // epilogue: act = silu(g)*u, store bf16
#pragma unroll
    for (int t = 0; t < MAXT; ++t) {
      if (t < nt) {
#pragma unroll
        for (int r = 0; r < 4; ++r) {
          int m = (tb + t) * 16 + kq * 4 + r;
          if (m < ne) {
            float gv = accg[t][r], uv = accu[t][r];
            float act = gv / (1.f + __expf(-gv)) * uv;
            reinterpret_cast<unsigned short*>(ACT)[(size_t)(base + m) * I_ + i0 + col] =
                f2bfbits(act);
          }
        }
      }
    }
  }
}

// ---------------- Down MFMA GEMM -> OUTS (fp32) ----------------
__global__ __launch_bounds__(256) void down_mfma(
    const __hip_bfloat16* __restrict__ ACT, const float* __restrict__ w2,
    const int* __restrict__ cnt, const int* __restrict__ off,
    float* __restrict__ OUTS) {
  int e = blockIdx.y;
  int ne = cnt[e];
  if (ne == 0) return;
  int base = off[e];
  int wv = threadIdx.x >> 6, lane = threadIdx.x & 63;
  int h0 = blockIdx.x * 64 + wv * 16;
  int col = lane & 15, kq = lane >> 4;

  const float* wp0 = w2 + (size_t)e * H_ * I_ + (size_t)(h0 + col) * I_ + kq * 8;

  int ntile = (ne + 15) >> 4;
  for (int tb = 0; tb < ntile; tb += MAXT) {
    int nt = ntile - tb; if (nt > MAXT) nt = MAXT;
    const __hip_bfloat16* arow[MAXT];
#pragma unroll
    for (int t = 0; t < MAXT; ++t) {
      int p = (tb + t) * 16 + col;
      int pc = p < ne ? p : ne - 1;
      arow[t] = ACT + (size_t)(base + pc) * I_ + kq * 8;
    }
    f32x4 acc[MAXT];
#pragma unroll
    for (int t = 0; t < MAXT; ++t) acc[t] = (f32x4){0.f, 0.f, 0.f, 0.f};
    const float* wp = wp0;
    for (int k = 0; k < I_; k += 32) {
      float4 w0 = *reinterpret_cast<const float4*>(wp);
      float4 w1 = *reinterpret_cast<const float4*>(wp + 4);
      bf16x8 bw = pack8(w0, w1);
#pragma unroll
      for (int t = 0; t < MAXT; ++t) {
        if (t < nt) {
          bf16x8 a = *reinterpret_cast<const bf16x8*>(arow[t]);
          acc[t] = mfma16(a, bw, acc[t]);
          arow[t] += 32;
        }
      }
      wp += 32;
    }
#pragma unroll
    for (int t = 0; t < MAXT; ++t) {
      if (t < nt) {
#pragma unroll
        for (int r = 0; r < 4; ++r) {
          int m = (tb + t) * 16 + kq * 4 + r;
          if (m < ne) {
            OUTS[(size_t)(base + m) * H_ + h0 + col] = acc[t][r];
          }
        }
      }
    }
  }
}

// ---------------- Weighted combine ----------------
__global__ __launch_bounds__(256) void combine_kernel(
    const float* __restrict__ OUTS, const float* __restrict__ topk_w,
    const int* __restrict__ slot2g, float* __restrict__ out) {
  int m = blockIdx.x;
  float w[K_]; int g[K_];
#pragma unroll
  for (int k = 0; k < K_; ++k) { w[k] = topk_w[m * K_ + k]; g[k] = slot2g[m * K_ + k]; }
  for (int h = threadIdx.x; h < H_; h += 256) {
    float s = 0.f;
#pragma unroll
    for (int k = 0; k < K_; ++k) s = fmaf(w[k], OUTS[(size_t)g[k] * H_ + h], s);
    out[(size_t)m * H_ + h] = s;
  }
}

extern "C" void kernel_launch(void* const* d_in, const int* in_sizes, int n_in,
                              void* d_out, int out_size, void* d_ws, size_t ws_size,
                              hipStream_t stream) {
  const float* x   = (const float*)d_in[0];
  const float* gw  = (const float*)d_in[1];
  const float* w13 = (const float*)d_in[2];
  const float* w2  = (const float*)d_in[3];
  float* out = (float*)d_out;

  const int M = in_sizes[0] / H_;   // 512
  const int MK = M * K_;            // 4096

  char* ws = (char*)d_ws;
  size_t o = 0;
  auto alloc = [&](size_t bytes) { size_t r = o; o = (o + bytes + 255) & ~(size_t)255; return r; };
  int*   topk_id  = (int*)(ws + alloc((size_t)MK * 4));
  float* topk_w   = (float*)(ws + alloc((size_t)MK * 4));
  int*   cnt      = (int*)(ws + alloc(E_ * 4));
  int*   off      = (int*)(ws + alloc((E_ + 1) * 4));
  int*   perEx    = (int*)(ws + alloc((size_t)E_ * M * 4));
  int*   entry_mk = (int*)(ws + alloc((size_t)MK * 4));
  int*   slot2g   = (int*)(ws + alloc((size_t)MK * 4));
  __hip_bfloat16* xb  = (__hip_bfloat16*)(ws + alloc((size_t)M * H_ * 2));
  __hip_bfloat16* ACT = (__hip_bfloat16*)(ws + alloc((size_t)MK * I_ * 2));
  float* OUTS     = (float*)(ws + alloc((size_t)MK * H_ * 4));
  (void)ws_size; (void)n_in; (void)out_size;

  cast_x_kernel<<<(M * H_ / 4 + 255) / 256, 256, 0, stream>>>(x, xb, M * H_ / 4);
  router_kernel<<<M, 256, 0, stream>>>(x, gw, topk_id, topk_w);
  zero_cnt_kernel<<<1, 256, 0, stream>>>(cnt);
  scatter_kernel<<<(MK + 255) / 256, 256, 0, stream>>>(topk_id, cnt, perEx, MK, M);
  scan_kernel<<<1, 64, 0, stream>>>(cnt, off);
  compact_kernel<<<E_, 256, 0, stream>>>(cnt, off, perEx, entry_mk, slot2g, M);
  gateup_mfma<<<dim3(I_ / 64, E_), 256, 0, stream>>>(xb, w13, cnt, off, entry_mk, ACT);
  down_mfma<<<dim3(H_ / 64, E_), 256, 0, stream>>>(ACT, w2, cnt, off, OUTS);
  combine_kernel<<<M, 256, 0, stream>>>(OUTS, topk_w, slot2g, out);
}

// Round 3
// 580.845 us; speedup vs baseline: 3.0956x; 1.1122x over previous
//
#include <hip/hip_runtime.h>
#include <hip/hip_bf16.h>

#define H_ 2048
#define E_ 64
#define I_ 768
#define K_ 8
#define GT 6   // token tiles per pass, gateup (96 tokens)
#define DT 8   // token tiles per pass, down (128 tokens)

typedef __attribute__((ext_vector_type(8))) __bf16 bf16x8;
typedef __attribute__((ext_vector_type(4))) float f32x4;

__device__ inline unsigned short f2bfbits(float f) {
  unsigned u = __float_as_uint(f);
  u = (u + 0x7fffu + ((u >> 16) & 1u)) >> 16;   // RNE
  return (unsigned short)u;
}
__device__ inline __bf16 f2bf(float f) {
  union { unsigned short s; __bf16 b; } cv; cv.s = f2bfbits(f); return cv.b;
}
__device__ inline f32x4 mfma16(bf16x8 a, bf16x8 b, f32x4 c) {
  return __builtin_amdgcn_mfma_f32_16x16x32_bf16(a, b, c, 0, 0, 0);
}
__device__ inline bf16x8 pack8(float4 a, float4 b) {
  bf16x8 r;
  r[0] = f2bf(a.x); r[1] = f2bf(a.y); r[2] = f2bf(a.z); r[3] = f2bf(a.w);
  r[4] = f2bf(b.x); r[5] = f2bf(b.y); r[6] = f2bf(b.z); r[7] = f2bf(b.w);
  return r;
}

// ---------------- Router (fp32-exact) ----------------
__global__ __launch_bounds__(256) void router_kernel(
    const float* __restrict__ x, const float* __restrict__ gw,
    int* __restrict__ topk_id, float* __restrict__ topk_w) {
  __shared__ float xs[H_];
  __shared__ float probs[E_];
  int m = blockIdx.x;
  const float* xr = x + (size_t)m * H_;
  for (int i = threadIdx.x; i < H_; i += 256) xs[i] = xr[i];
  __syncthreads();
  int e = threadIdx.x >> 2, part = threadIdx.x & 3;
  const float* gr = gw + (size_t)e * H_ + part * (H_ / 4);
  const float* xx = xs + part * (H_ / 4);
  float s = 0.f;
#pragma unroll 8
  for (int i = 0; i < H_ / 4; ++i) s = fmaf(xx[i], gr[i], s);
  s += __shfl_xor(s, 1);
  s += __shfl_xor(s, 2);
  if (part == 0) probs[e] = s;
  __syncthreads();
  if (threadIdx.x == 0) {
    float mx = -1e30f;
    for (int i = 0; i < E_; ++i) mx = fmaxf(mx, probs[i]);
    float sum = 0.f;
    for (int i = 0; i < E_; ++i) { float p = expf(probs[i] - mx); probs[i] = p; sum += p; }
    float inv = 1.f / sum;
    for (int i = 0; i < E_; ++i) probs[i] *= inv;
    float bw[K_]; int bi[K_]; float wsum = 0.f;
#pragma unroll
    for (int k = 0; k < K_; ++k) {
      float best = -1.f; int b = 0;
      for (int i = 0; i < E_; ++i) if (probs[i] > best) { best = probs[i]; b = i; }
      bw[k] = best; bi[k] = b; wsum += best; probs[b] = -2.f;
    }
    float winv = 1.f / wsum;
#pragma unroll
    for (int k = 0; k < K_; ++k) {
      topk_id[m * K_ + k] = bi[k];
      topk_w[m * K_ + k] = bw[k] * winv;
    }
  }
}

// ---------------- Expert list build ----------------
__global__ void zero_cnt_kernel(int* cnt) {
  if (threadIdx.x < E_) cnt[threadIdx.x] = 0;
}

__global__ void scatter_kernel(const int* __restrict__ topk_id, int* cnt,
                               int* perEx, int MK, int M) {
  int idx = blockIdx.x * 256 + threadIdx.x;
  if (idx >= MK) return;
  int e = topk_id[idx];
  int pos = atomicAdd(cnt + e, 1);
  perEx[e * M + pos] = idx;  // idx == m*K_+k
}

__global__ void scan_kernel(const int* cnt, int* off) {
  if (threadIdx.x == 0) {
    int a = 0;
    for (int e = 0; e < E_; ++e) { off[e] = a; a += cnt[e]; }
    off[E_] = a;
  }
}

__global__ void compact_kernel(const int* __restrict__ cnt, const int* __restrict__ off,
                               const int* __restrict__ perEx,
                               int* __restrict__ entry_mk, int* __restrict__ slot2g, int M) {
  int e = blockIdx.x; int n = cnt[e]; int b = off[e];
  for (int p = threadIdx.x; p < n; p += 256) {
    int mk = perEx[e * M + p];
    entry_mk[b + p] = mk;
    slot2g[mk] = b + p;
  }
}

// ---------------- x -> bf16 ----------------
__global__ __launch_bounds__(256) void cast_x_kernel(
    const float* __restrict__ x, __hip_bfloat16* __restrict__ xb, int n4) {
  int i = blockIdx.x * 256 + threadIdx.x;
  if (i >= n4) return;
  float4 v = reinterpret_cast<const float4*>(x)[i];
  short4 s;
  s.x = (short)f2bfbits(v.x); s.y = (short)f2bfbits(v.y);
  s.z = (short)f2bfbits(v.z); s.w = (short)f2bfbits(v.w);
  reinterpret_cast<short4*>(xb)[i] = s;
}

// ---------------- Gate/Up MFMA GEMM + SiLU -> ACT (bf16) ----------------
// Wave: 16 i-cols (gate+up), GT*16 tokens, K=H streamed; weight loads rotated
// one K-step ahead; all token tiles computed unconditionally (clamped pads).
__global__ __launch_bounds__(256) void gateup_mfma(
    const __hip_bfloat16* __restrict__ xb, const float* __restrict__ w13,
    const int* __restrict__ cnt, const int* __restrict__ off,
    const int* __restrict__ entry_mk, __hip_bfloat16* __restrict__ ACT) {
  int e = blockIdx.y;
  int ne = cnt[e];
  if (ne == 0) return;
  int base = off[e];
  int wv = threadIdx.x >> 6, lane = threadIdx.x & 63;
  int i0 = blockIdx.x * 64 + wv * 16;
  int col = lane & 15, kq = lane >> 4;

  const float* wg0 = w13 + (size_t)e * (2 * I_) * H_ + (size_t)(i0 + col) * H_ + kq * 8;
  const float* wu0 = wg0 + (size_t)I_ * H_;

  int ntile = (ne + 15) >> 4;
  for (int tb = 0; tb < ntile; tb += GT) {
    const __hip_bfloat16* arow[GT];
#pragma unroll
    for (int t = 0; t < GT; ++t) {
      int p = (tb + t) * 16 + col;
      int pc = p < ne ? p : ne - 1;
      int tok = entry_mk[base + pc] >> 3;
      arow[t] = xb + (size_t)tok * H_ + kq * 8;
    }
    f32x4 accg[GT], accu[GT];
#pragma unroll
    for (int t = 0; t < GT; ++t) {
      accg[t] = (f32x4){0.f, 0.f, 0.f, 0.f};
      accu[t] = (f32x4){0.f, 0.f, 0.f, 0.f};
    }
    const float* wg = wg0;
    const float* wu = wu0;
    float4 g0 = *reinterpret_cast<const float4*>(wg);
    float4 g1 = *reinterpret_cast<const float4*>(wg + 4);
    float4 u0 = *reinterpret_cast<const float4*>(wu);
    float4 u1 = *reinterpret_cast<const float4*>(wu + 4);
#pragma unroll 1
    for (int k = 0; k < H_ - 32; k += 32) {
      float4 ng0 = *reinterpret_cast<const float4*>(wg + 32);
      float4 ng1 = *reinterpret_cast<const float4*>(wg + 36);
      float4 nu0 = *reinterpret_cast<const float4*>(wu + 32);
      float4 nu1 = *reinterpret_cast<const float4*>(wu + 36);
      bf16x8 bg = pack8(g0, g1);
      bf16x8 bu = pack8(u0, u1);
#pragma unroll
      for (int t = 0; t < GT; ++t) {
        bf16x8 a = *reinterpret_cast<const bf16x8*>(arow[t]);
        accg[t] = mfma16(a, bg, accg[t]);
        accu[t] = mfma16(a, bu, accu[t]);
        arow[t] += 32;
      }
      g0 = ng0; g1 = ng1; u0 = nu0; u1 = nu1;
      wg += 32; wu += 32;
    }
    {
      bf16x8 bg = pack8(g0, g1);
      bf16x8 bu = pack8(u0, u1);
#pragma unroll
      for (int t = 0; t < GT; ++t) {
        bf16x8 a = *reinterpret_cast<const bf16x8*>(arow[t]);
        accg[t] = mfma16(a, bg, accg[t]);
        accu[t] = mfma16(a, bu, accu[t]);
      }
    }
    // epilogue: act = silu(g)*u, store bf16
#pragma unroll
    for (int t = 0; t < GT; ++t) {
#pragma unroll
      for (int r = 0; r < 4; ++r) {
        int m = (tb + t) * 16 + kq * 4 + r;
        if (m < ne) {
          float gv = accg[t][r], uv = accu[t][r];
          float act = gv / (1.f + __expf(-gv)) * uv;
          reinterpret_cast<unsigned short*>(ACT)[(size_t)(base + m) * I_ + i0 + col] =
              f2bfbits(act);
        }
      }
    }
  }
}

// ---------------- Down MFMA GEMM -> OUTS (fp32) ----------------
__global__ __launch_bounds__(256) void down_mfma(
    const __hip_bfloat16* __restrict__ ACT, const float* __restrict__ w2,
    const int* __restrict__ cnt, const int* __restrict__ off,
    float* __restrict__ OUTS) {
  int e = blockIdx.y;
  int ne = cnt[e];
  if (ne == 0) return;
  int base = off[e];
  int wv = threadIdx.x >> 6, lane = threadIdx.x & 63;
  int h0 = blockIdx.x * 64 + wv * 16;
  int col = lane & 15, kq = lane >> 4;

  const float* wp0 = w2 + (size_t)e * H_ * I_ + (size_t)(h0 + col) * I_ + kq * 8;

  int ntile = (ne + 15) >> 4;
  for (int tb = 0; tb < ntile; tb += DT) {
    const __hip_bfloat16* arow[DT];
#pragma unroll
    for (int t = 0; t < DT; ++t) {
      int p = (tb + t) * 16 + col;
      int pc = p < ne ? p : ne - 1;
      arow[t] = ACT + (size_t)(base + pc) * I_ + kq * 8;
    }
    f32x4 acc[DT];
#pragma unroll
    for (int t = 0; t < DT; ++t) acc[t] = (f32x4){0.f, 0.f, 0.f, 0.f};
    const float* wp = wp0;
    float4 w0 = *reinterpret_cast<const float4*>(wp);
    float4 w1 = *reinterpret_cast<const float4*>(wp + 4);
#pragma unroll 1
    for (int k = 0; k < I_ - 32; k += 32) {
      float4 nw0 = *reinterpret_cast<const float4*>(wp + 32);
      float4 nw1 = *reinterpret_cast<const float4*>(wp + 36);
      bf16x8 bw = pack8(w0, w1);
#pragma unroll
      for (int t = 0; t < DT; ++t) {
        bf16x8 a = *reinterpret_cast<const bf16x8*>(arow[t]);
        acc[t] = mfma16(a, bw, acc[t]);
        arow[t] += 32;
      }
      w0 = nw0; w1 = nw1;
      wp += 32;
    }
    {
      bf16x8 bw = pack8(w0, w1);
#pragma unroll
      for (int t = 0; t < DT; ++t) {
        bf16x8 a = *reinterpret_cast<const bf16x8*>(arow[t]);
        acc[t] = mfma16(a, bw, acc[t]);
      }
    }
#pragma unroll
    for (int t = 0; t < DT; ++t) {
#pragma unroll
      for (int r = 0; r < 4; ++r) {
        int m = (tb + t) * 16 + kq * 4 + r;
        if (m < ne) {
          OUTS[(size_t)(base + m) * H_ + h0 + col] = acc[t][r];
        }
      }
    }
  }
}

// ---------------- Weighted combine ----------------
__global__ __launch_bounds__(256) void combine_kernel(
    const float* __restrict__ OUTS, const float* __restrict__ topk_w,
    const int* __restrict__ slot2g, float* __restrict__ out) {
  int m = blockIdx.x;
  float w[K_]; int g[K_];
#pragma unroll
  for (int k = 0; k < K_; ++k) { w[k] = topk_w[m * K_ + k]; g[k] = slot2g[m * K_ + k]; }
  for (int h = threadIdx.x; h < H_; h += 256) {
    float s = 0.f;
#pragma unroll
    for (int k = 0; k < K_; ++k) s = fmaf(w[k], OUTS[(size_t)g[k] * H_ + h], s);
    out[(size_t)m * H_ + h] = s;
  }
}

extern "C" void kernel_launch(void* const* d_in, const int* in_sizes, int n_in,
                              void* d_out, int out_size, void* d_ws, size_t ws_size,
                              hipStream_t stream) {
  const float* x   = (const float*)d_in[0];
  const float* gw  = (const float*)d_in[1];
  const float* w13 = (const float*)d_in[2];
  const float* w2  = (const float*)d_in[3];
  float* out = (float*)d_out;

  const int M = in_sizes[0] / H_;   // 512
  const int MK = M * K_;            // 4096

  char* ws = (char*)d_ws;
  size_t o = 0;
  auto alloc = [&](size_t bytes) { size_t r = o; o = (o + bytes + 255) & ~(size_t)255; return r; };
  int*   topk_id  = (int*)(ws + alloc((size_t)MK * 4));
  float* topk_w   = (float*)(ws + alloc((size_t)MK * 4));
  int*   cnt      = (int*)(ws + alloc(E_ * 4));
  int*   off      = (int*)(ws + alloc((E_ + 1) * 4));
  int*   perEx    = (int*)(ws + alloc((size_t)E_ * M * 4));
  int*   entry_mk = (int*)(ws + alloc((size_t)MK * 4));
  int*   slot2g   = (int*)(ws + alloc((size_t)MK * 4));
  __hip_bfloat16* xb  = (__hip_bfloat16*)(ws + alloc((size_t)M * H_ * 2));
  __hip_bfloat16* ACT = (__hip_bfloat16*)(ws + alloc((size_t)MK * I_ * 2));
  float* OUTS     = (float*)(ws + alloc((size_t)MK * H_ * 4));
  (void)ws_size; (void)n_in; (void)out_size;

  cast_x_kernel<<<(M * H_ / 4 + 255) / 256, 256, 0, stream>>>(x, xb, M * H_ / 4);
  router_kernel<<<M, 256, 0, stream>>>(x, gw, topk_id, topk_w);
  zero_cnt_kernel<<<1, 256, 0, stream>>>(cnt);
  scatter_kernel<<<(MK + 255) / 256, 256, 0, stream>>>(topk_id, cnt, perEx, MK, M);
  scan_kernel<<<1, 64, 0, stream>>>(cnt, off);
  compact_kernel<<<E_, 256, 0, stream>>>(cnt, off, perEx, entry_mk, slot2g, M);
  gateup_mfma<<<dim3(I_ / 64, E_), 256, 0, stream>>>(xb, w13, cnt, off, entry_mk, ACT);
  down_mfma<<<dim3(H_ / 64, E_), 256, 0, stream>>>(ACT, w2, cnt, off, OUTS);
  combine_kernel<<<M, 256, 0, stream>>>(OUTS, topk_w, slot2g, out);
}

// Round 4
// 501.427 us; speedup vs baseline: 3.5859x; 1.1584x over previous
//
#include <hip/hip_runtime.h>
#include <hip/hip_bf16.h>

#define H_ 2048
#define E_ 64
#define I_ 768
#define K_ 8
#define GT 5          // 16-row token tiles per pass (80 tokens)
#define BKF 32        // K-chunk in floats

typedef __attribute__((ext_vector_type(8))) __bf16 bf16x8;
typedef __attribute__((ext_vector_type(4))) float f32x4;

__device__ inline unsigned short f2bfbits(float f) {
  unsigned u = __float_as_uint(f);
  u = (u + 0x7fffu + ((u >> 16) & 1u)) >> 16;   // RNE
  return (unsigned short)u;
}
__device__ inline __bf16 f2bf(float f) {
  union { unsigned short s; __bf16 b; } cv; cv.s = f2bfbits(f); return cv.b;
}
__device__ inline f32x4 mfma16(bf16x8 a, bf16x8 b, f32x4 c) {
  return __builtin_amdgcn_mfma_f32_16x16x32_bf16(a, b, c, 0, 0, 0);
}
__device__ inline bf16x8 pack8(float4 a, float4 b) {
  bf16x8 r;
  r[0] = f2bf(a.x); r[1] = f2bf(a.y); r[2] = f2bf(a.z); r[3] = f2bf(a.w);
  r[4] = f2bf(b.x); r[5] = f2bf(b.y); r[6] = f2bf(b.z); r[7] = f2bf(b.w);
  return r;
}
// async global->LDS, 16B per lane; dest must be wave-uniform base (lane*16 implicit)
__device__ inline void dma16(const float* g, float* l) {
  __builtin_amdgcn_global_load_lds(
      (const __attribute__((address_space(1))) float*)g,
      (__attribute__((address_space(3))) float*)l, 16, 0, 0);
}
// raw barrier with compiler memory fences (NOT __syncthreads: that drains vmcnt(0))
__device__ inline void fence_sync() {
  asm volatile("" ::: "memory");
  __builtin_amdgcn_s_barrier();
  asm volatile("" ::: "memory");
}

// ---------------- Router (fp32-exact) + fused x->bf16 cast ----------------
__global__ __launch_bounds__(256) void router_kernel(
    const float* __restrict__ x, const float* __restrict__ gw,
    int* __restrict__ topk_id, float* __restrict__ topk_w,
    __hip_bfloat16* __restrict__ xb) {
  __shared__ float xs[H_];
  __shared__ float probs[E_];
  int m = blockIdx.x;
  const float* xr = x + (size_t)m * H_;
  for (int i = threadIdx.x; i < H_; i += 256) xs[i] = xr[i];
  __syncthreads();
  // fused cast of this token row to bf16
  unsigned short* xbr = reinterpret_cast<unsigned short*>(xb) + (size_t)m * H_;
  for (int i = threadIdx.x; i < H_; i += 256) xbr[i] = f2bfbits(xs[i]);
  int e = threadIdx.x >> 2, part = threadIdx.x & 3;
  const float* gr = gw + (size_t)e * H_ + part * (H_ / 4);
  const float* xx = xs + part * (H_ / 4);
  float s = 0.f;
#pragma unroll 8
  for (int i = 0; i < H_ / 4; ++i) s = fmaf(xx[i], gr[i], s);
  s += __shfl_xor(s, 1);
  s += __shfl_xor(s, 2);
  if (part == 0) probs[e] = s;
  __syncthreads();
  if (threadIdx.x == 0) {
    float mx = -1e30f;
    for (int i = 0; i < E_; ++i) mx = fmaxf(mx, probs[i]);
    float sum = 0.f;
    for (int i = 0; i < E_; ++i) { float p = expf(probs[i] - mx); probs[i] = p; sum += p; }
    float inv = 1.f / sum;
    for (int i = 0; i < E_; ++i) probs[i] *= inv;
    float bw[K_]; int bi[K_]; float wsum = 0.f;
#pragma unroll
    for (int k = 0; k < K_; ++k) {
      float best = -1.f; int b = 0;
      for (int i = 0; i < E_; ++i) if (probs[i] > best) { best = probs[i]; b = i; }
      bw[k] = best; bi[k] = b; wsum += best; probs[b] = -2.f;
    }
    float winv = 1.f / wsum;
#pragma unroll
    for (int k = 0; k < K_; ++k) {
      topk_id[m * K_ + k] = bi[k];
      topk_w[m * K_ + k] = bw[k] * winv;
    }
  }
}

// ---------------- Expert list build ----------------
__global__ void zero_cnt_kernel(int* cnt) {
  if (threadIdx.x < E_) cnt[threadIdx.x] = 0;
}

__global__ void scatter_kernel(const int* __restrict__ topk_id, int* cnt,
                               int* perEx, int MK, int M) {
  int idx = blockIdx.x * 256 + threadIdx.x;
  if (idx >= MK) return;
  int e = topk_id[idx];
  int pos = atomicAdd(cnt + e, 1);
  perEx[e * M + pos] = idx;  // idx == m*K_+k
}

__global__ void scan_kernel(const int* cnt, int* off) {
  if (threadIdx.x == 0) {
    int a = 0;
    for (int e = 0; e < E_; ++e) { off[e] = a; a += cnt[e]; }
    off[E_] = a;
  }
}

__global__ void compact_kernel(const int* __restrict__ cnt, const int* __restrict__ off,
                               const int* __restrict__ perEx,
                               int* __restrict__ entry_mk, int* __restrict__ slot2g, int M) {
  int e = blockIdx.x; int n = cnt[e]; int b = off[e];
  for (int p = threadIdx.x; p < n; p += 256) {
    int mk = perEx[e * M + p];
    entry_mk[b + p] = mk;
    slot2g[mk] = b + p;
  }
}

// ---------------- Gate/Up MFMA GEMM + SiLU -> ACT (bf16) ----------------
// Block: 64 i-cols (gate+up), 4 waves x 16 cols. Weights DMA'd fp32 -> LDS
// (2x16KB dbuf, XOR-swizzled src/read), tokens reg-ping-pong, counted vmcnt.
__global__ __launch_bounds__(256, 2) void gateup_mfma(
    const __hip_bfloat16* __restrict__ xb, const float* __restrict__ w13,
    const int* __restrict__ cnt, const int* __restrict__ off,
    const int* __restrict__ entry_mk, __hip_bfloat16* __restrict__ ACT) {
  __shared__ __align__(16) float lds[2][128 * BKF];
  int e = blockIdx.y;
  int ne = cnt[e];
  if (ne == 0) return;
  int base = off[e];
  int wv = threadIdx.x >> 6, lane = threadIdx.x & 63;
  int i0 = blockIdx.x * 64;
  int col = lane & 15, kq = lane >> 4;
  int myrow = wv * 16 + col;               // gate row in [0,64)
  int s0 = (2 * kq) ^ (col & 7);           // swizzled float4 slot
  const float* w13e = w13 + (size_t)e * (2 * I_) * H_;

  // per-lane DMA source addrs (chunk c = wv*4+q; rows 8c..8c+7; c>=8 -> up)
  const float* dsrc[4];
#pragma unroll
  for (int q = 0; q < 4; ++q) {
    int c = wv * 4 + q;
    int r = 8 * (c & 7) + (lane >> 3);
    int j = (lane & 7) ^ ((lane >> 3) & 7);
    size_t row = (size_t)(i0 + r) + (c >= 8 ? (size_t)I_ : (size_t)0);
    dsrc[q] = w13e + row * H_ + (size_t)j * 4;
  }

  const int NCH = H_ / BKF;  // 64
  int ntile = (ne + 15) >> 4;
  for (int tb = 0; tb < ntile; tb += GT) {
    const __hip_bfloat16* arow0[GT];
#pragma unroll
    for (int t = 0; t < GT; ++t) {
      int p = (tb + t) * 16 + col;
      int pc = p < ne ? p : ne - 1;
      int tok = entry_mk[base + pc] >> 3;
      arow0[t] = xb + (size_t)tok * H_ + kq * 8;
    }
    f32x4 accg[GT], accu[GT];
#pragma unroll
    for (int t = 0; t < GT; ++t) {
      accg[t] = (f32x4){0.f, 0.f, 0.f, 0.f};
      accu[t] = (f32x4){0.f, 0.f, 0.f, 0.f};
    }
    bf16x8 aA[GT], aB[GT];
#pragma unroll
    for (int t = 0; t < GT; ++t) aA[t] = *reinterpret_cast<const bf16x8*>(arow0[t]);
#pragma unroll
    for (int q = 0; q < 4; ++q) dma16(dsrc[q], &lds[0][(wv * 4 + q) * 256]);

    auto step = [&](int n, bf16x8 (&ac)[GT], bf16x8 (&an)[GT],
                    const float* ldsC, float* ldsN) {
      if (n + 1 < NCH) {
        size_t ko = (size_t)(n + 1) * BKF;
#pragma unroll
        for (int t = 0; t < GT; ++t)
          an[t] = *reinterpret_cast<const bf16x8*>(arow0[t] + ko);
#pragma unroll
        for (int q = 0; q < 4; ++q)
          dma16(dsrc[q] + ko, ldsN + (wv * 4 + q) * 256);
        asm volatile("s_waitcnt vmcnt(9)" ::: "memory");   // 5 A + 4 DMA newest
      } else {
        asm volatile("s_waitcnt vmcnt(0)" ::: "memory");
      }
      __builtin_amdgcn_sched_barrier(0);
      fence_sync();
      const float4* L = reinterpret_cast<const float4*>(ldsC);
      float4 g0 = L[myrow * 8 + s0];
      float4 g1 = L[myrow * 8 + (s0 ^ 1)];
      float4 u0 = L[(64 + myrow) * 8 + s0];
      float4 u1 = L[(64 + myrow) * 8 + (s0 ^ 1)];
      bf16x8 bg = pack8(g0, g1);
      bf16x8 bu = pack8(u0, u1);
#pragma unroll
      for (int t = 0; t < GT; ++t) {
        accg[t] = mfma16(ac[t], bg, accg[t]);
        accu[t] = mfma16(ac[t], bu, accu[t]);
      }
      asm volatile("s_waitcnt lgkmcnt(0)" ::: "memory");
      __builtin_amdgcn_sched_barrier(0);
      fence_sync();
    };
    for (int n = 0; n < NCH; n += 2) {
      step(n,     aA, aB, lds[0], lds[1]);
      step(n + 1, aB, aA, lds[1], lds[0]);
    }
    // epilogue: act = silu(g)*u -> bf16
#pragma unroll
    for (int t = 0; t < GT; ++t) {
#pragma unroll
      for (int r = 0; r < 4; ++r) {
        int m = (tb + t) * 16 + kq * 4 + r;
        if (m < ne) {
          float gv = accg[t][r], uv = accu[t][r];
          float act = gv / (1.f + __expf(-gv)) * uv;
          reinterpret_cast<unsigned short*>(ACT)[(size_t)(base + m) * I_ + i0 + myrow] =
              f2bfbits(act);
        }
      }
    }
  }
}

// ---------------- Down MFMA GEMM -> OUTS (fp32) ----------------
__global__ __launch_bounds__(256, 2) void down_mfma(
    const __hip_bfloat16* __restrict__ ACT, const float* __restrict__ w2,
    const int* __restrict__ cnt, const int* __restrict__ off,
    float* __restrict__ OUTS) {
  __shared__ __align__(16) float lds[2][64 * BKF];
  int e = blockIdx.y;
  int ne = cnt[e];
  if (ne == 0) return;
  int base = off[e];
  int wv = threadIdx.x >> 6, lane = threadIdx.x & 63;
  int h0 = blockIdx.x * 64;
  int col = lane & 15, kq = lane >> 4;
  int myrow = wv * 16 + col;
  int s0 = (2 * kq) ^ (col & 7);
  const float* w2e = w2 + (size_t)e * H_ * I_;

  const float* dsrc[2];
#pragma unroll
  for (int q = 0; q < 2; ++q) {
    int c = wv * 2 + q;
    int r = 8 * c + (lane >> 3);
    int j = (lane & 7) ^ ((lane >> 3) & 7);
    dsrc[q] = w2e + (size_t)(h0 + r) * I_ + (size_t)j * 4;
  }

  const int NCH = I_ / BKF;  // 24
  int ntile = (ne + 15) >> 4;
  for (int tb = 0; tb < ntile; tb += GT) {
    const __hip_bfloat16* arow0[GT];
#pragma unroll
    for (int t = 0; t < GT; ++t) {
      int p = (tb + t) * 16 + col;
      int pc = p < ne ? p : ne - 1;
      arow0[t] = ACT + (size_t)(base + pc) * I_ + kq * 8;
    }
    f32x4 acc[GT];
#pragma unroll
    for (int t = 0; t < GT; ++t) acc[t] = (f32x4){0.f, 0.f, 0.f, 0.f};
    bf16x8 aA[GT], aB[GT];
#pragma unroll
    for (int t = 0; t < GT; ++t) aA[t] = *reinterpret_cast<const bf16x8*>(arow0[t]);
#pragma unroll
    for (int q = 0; q < 2; ++q) dma16(dsrc[q], &lds[0][(wv * 2 + q) * 256]);

    auto step = [&](int n, bf16x8 (&ac)[GT], bf16x8 (&an)[GT],
                    const float* ldsC, float* ldsN) {
      if (n + 1 < NCH) {
        size_t ko = (size_t)(n + 1) * BKF;
#pragma unroll
        for (int t = 0; t < GT; ++t)
          an[t] = *reinterpret_cast<const bf16x8*>(arow0[t] + ko);
#pragma unroll
        for (int q = 0; q < 2; ++q)
          dma16(dsrc[q] + ko, ldsN + (wv * 2 + q) * 256);
        asm volatile("s_waitcnt vmcnt(7)" ::: "memory");   // 5 A + 2 DMA newest
      } else {
        asm volatile("s_waitcnt vmcnt(0)" ::: "memory");
      }
      __builtin_amdgcn_sched_barrier(0);
      fence_sync();
      const float4* L = reinterpret_cast<const float4*>(ldsC);
      float4 w0 = L[myrow * 8 + s0];
      float4 w1 = L[myrow * 8 + (s0 ^ 1)];
      bf16x8 bw = pack8(w0, w1);
#pragma unroll
      for (int t = 0; t < GT; ++t) acc[t] = mfma16(ac[t], bw, acc[t]);
      asm volatile("s_waitcnt lgkmcnt(0)" ::: "memory");
      __builtin_amdgcn_sched_barrier(0);
      fence_sync();
    };
    for (int n = 0; n < NCH; n += 2) {
      step(n,     aA, aB, lds[0], lds[1]);
      step(n + 1, aB, aA, lds[1], lds[0]);
    }
#pragma unroll
    for (int t = 0; t < GT; ++t) {
#pragma unroll
      for (int r = 0; r < 4; ++r) {
        int m = (tb + t) * 16 + kq * 4 + r;
        if (m < ne) {
          OUTS[(size_t)(base + m) * H_ + h0 + myrow] = acc[t][r];
        }
      }
    }
  }
}

// ---------------- Weighted combine ----------------
__global__ __launch_bounds__(256) void combine_kernel(
    const float* __restrict__ OUTS, const float* __restrict__ topk_w,
    const int* __restrict__ slot2g, float* __restrict__ out) {
  int m = blockIdx.x;
  float w[K_]; int g[K_];
#pragma unroll
  for (int k = 0; k < K_; ++k) { w[k] = topk_w[m * K_ + k]; g[k] = slot2g[m * K_ + k]; }
  for (int h = threadIdx.x; h < H_; h += 256) {
    float s = 0.f;
#pragma unroll
    for (int k = 0; k < K_; ++k) s = fmaf(w[k], OUTS[(size_t)g[k] * H_ + h], s);
    out[(size_t)m * H_ + h] = s;
  }
}

extern "C" void kernel_launch(void* const* d_in, const int* in_sizes, int n_in,
                              void* d_out, int out_size, void* d_ws, size_t ws_size,
                              hipStream_t stream) {
  const float* x   = (const float*)d_in[0];
  const float* gw  = (const float*)d_in[1];
  const float* w13 = (const float*)d_in[2];
  const float* w2  = (const float*)d_in[3];
  float* out = (float*)d_out;

  const int M = in_sizes[0] / H_;   // 512
  const int MK = M * K_;            // 4096

  char* ws = (char*)d_ws;
  size_t o = 0;
  auto alloc = [&](size_t bytes) { size_t r = o; o = (o + bytes + 255) & ~(size_t)255; return r; };
  int*   topk_id  = (int*)(ws + alloc((size_t)MK * 4));
  float* topk_w   = (float*)(ws + alloc((size_t)MK * 4));
  int*   cnt      = (int*)(ws + alloc(E_ * 4));
  int*   off      = (int*)(ws + alloc((E_ + 1) * 4));
  int*   perEx    = (int*)(ws + alloc((size_t)E_ * M * 4));
  int*   entry_mk = (int*)(ws + alloc((size_t)MK * 4));
  int*   slot2g   = (int*)(ws + alloc((size_t)MK * 4));
  __hip_bfloat16* xb  = (__hip_bfloat16*)(ws + alloc((size_t)M * H_ * 2));
  __hip_bfloat16* ACT = (__hip_bfloat16*)(ws + alloc((size_t)MK * I_ * 2));
  float* OUTS     = (float*)(ws + alloc((size_t)MK * H_ * 4));
  (void)ws_size; (void)n_in; (void)out_size;

  router_kernel<<<M, 256, 0, stream>>>(x, gw, topk_id, topk_w, xb);
  zero_cnt_kernel<<<1, 256, 0, stream>>>(cnt);
  scatter_kernel<<<(MK + 255) / 256, 256, 0, stream>>>(topk_id, cnt, perEx, MK, M);
  scan_kernel<<<1, 64, 0, stream>>>(cnt, off);
  compact_kernel<<<E_, 256, 0, stream>>>(cnt, off, perEx, entry_mk, slot2g, M);
  gateup_mfma<<<dim3(I_ / 64, E_), 256, 0, stream>>>(xb, w13, cnt, off, entry_mk, ACT);
  down_mfma<<<dim3(H_ / 64, E_), 256, 0, stream>>>(ACT, w2, cnt, off, OUTS);
  combine_kernel<<<M, 256, 0, stream>>>(OUTS, topk_w, slot2g, out);
}

// Round 5
// 469.024 us; speedup vs baseline: 3.8337x; 1.0691x over previous
//
#include <hip/hip_runtime.h>
#include <hip/hip_bf16.h>

#define H_ 2048
#define E_ 64
#define I_ 768
#define K_ 8
#define GT 5          // 16-row token tiles per pass (80 tokens)
#define BKF 32        // K-chunk in elements (128 B fp32 per row)

typedef __attribute__((ext_vector_type(8))) __bf16 bf16x8;
typedef __attribute__((ext_vector_type(4))) float f32x4;

__device__ inline unsigned short f2bfbits(float f) {
  unsigned u = __float_as_uint(f);
  u = (u + 0x7fffu + ((u >> 16) & 1u)) >> 16;   // RNE
  return (unsigned short)u;
}
__device__ inline __bf16 f2bf(float f) {
  union { unsigned short s; __bf16 b; } cv; cv.s = f2bfbits(f); return cv.b;
}
__device__ inline f32x4 mfma16(bf16x8 a, bf16x8 b, f32x4 c) {
  return __builtin_amdgcn_mfma_f32_16x16x32_bf16(a, b, c, 0, 0, 0);
}
__device__ inline bf16x8 packv(f32x4 a, f32x4 b) {
  bf16x8 r;
  r[0] = f2bf(a[0]); r[1] = f2bf(a[1]); r[2] = f2bf(a[2]); r[3] = f2bf(a[3]);
  r[4] = f2bf(b[0]); r[5] = f2bf(b[1]); r[6] = f2bf(b[2]); r[7] = f2bf(b[3]);
  return r;
}
// async global->LDS, 16B/lane; LDS dest = wave-uniform base + lane*16 (implicit)
__device__ inline void dma16(const float* g, float* l) {
  __builtin_amdgcn_global_load_lds(
      (const __attribute__((address_space(1))) float*)g,
      (__attribute__((address_space(3))) float*)l, 16, 0, 0);
}
#define SB() __builtin_amdgcn_sched_barrier(0)

// ---------------- Router (fp32-exact) + fused x->bf16 cast + cnt zero --------
__global__ __launch_bounds__(256) void router_kernel(
    const float* __restrict__ x, const float* __restrict__ gw,
    int* __restrict__ topk_id, float* __restrict__ topk_w,
    __hip_bfloat16* __restrict__ xb, int* __restrict__ cnt) {
  __shared__ float xs[H_];
  __shared__ float probs[E_];
  int m = blockIdx.x;
  if (m == 0 && threadIdx.x < E_) cnt[threadIdx.x] = 0;
  const float* xr = x + (size_t)m * H_;
  for (int i = threadIdx.x; i < H_; i += 256) xs[i] = xr[i];
  __syncthreads();
  unsigned short* xbr = reinterpret_cast<unsigned short*>(xb) + (size_t)m * H_;
  for (int i = threadIdx.x; i < H_; i += 256) xbr[i] = f2bfbits(xs[i]);
  int e = threadIdx.x >> 2, part = threadIdx.x & 3;
  const float* gr = gw + (size_t)e * H_ + part * (H_ / 4);
  const float* xx = xs + part * (H_ / 4);
  float s = 0.f;
#pragma unroll 8
  for (int i = 0; i < H_ / 4; ++i) s = fmaf(xx[i], gr[i], s);
  s += __shfl_xor(s, 1);
  s += __shfl_xor(s, 2);
  if (part == 0) probs[e] = s;
  __syncthreads();
  if (threadIdx.x == 0) {
    float mx = -1e30f;
    for (int i = 0; i < E_; ++i) mx = fmaxf(mx, probs[i]);
    float sum = 0.f;
    for (int i = 0; i < E_; ++i) { float p = expf(probs[i] - mx); probs[i] = p; sum += p; }
    float inv = 1.f / sum;
    for (int i = 0; i < E_; ++i) probs[i] *= inv;
    float bw[K_]; int bi[K_]; float wsum = 0.f;
#pragma unroll
    for (int k = 0; k < K_; ++k) {
      float best = -1.f; int b = 0;
      for (int i = 0; i < E_; ++i) if (probs[i] > best) { best = probs[i]; b = i; }
      bw[k] = best; bi[k] = b; wsum += best; probs[b] = -2.f;
    }
    float winv = 1.f / wsum;
#pragma unroll
    for (int k = 0; k < K_; ++k) {
      topk_id[m * K_ + k] = bi[k];
      topk_w[m * K_ + k] = bw[k] * winv;
    }
  }
}

// ---------------- Expert list build ----------------
__global__ void scatter_kernel(const int* __restrict__ topk_id, int* cnt,
                               int* perEx, int MK, int M) {
  int idx = blockIdx.x * 256 + threadIdx.x;
  if (idx >= MK) return;
  int e = topk_id[idx];
  int pos = atomicAdd(cnt + e, 1);
  perEx[e * M + pos] = idx;  // idx == m*K_+k
}

__global__ void scan_kernel(const int* cnt, int* off) {
  if (threadIdx.x == 0) {
    int a = 0;
    for (int e = 0; e < E_; ++e) { off[e] = a; a += cnt[e]; }
    off[E_] = a;
  }
}

__global__ void compact_kernel(const int* __restrict__ cnt, const int* __restrict__ off,
                               const int* __restrict__ perEx,
                               int* __restrict__ entry_mk, int* __restrict__ slot2g, int M) {
  int e = blockIdx.x; int n = cnt[e]; int b = off[e];
  for (int p = threadIdx.x; p < n; p += 256) {
    int mk = perEx[e * M + p];
    entry_mk[b + p] = mk;
    slot2g[mk] = b + p;
  }
}

// ---------------- Gate/Up MFMA GEMM + SiLU -> ACT (bf16) ----------------
// Wave-private LDS triple-buffer, depth-2 DMA prefetch, no barriers.
__global__ __launch_bounds__(256, 3) void gateup_mfma(
    const __hip_bfloat16* __restrict__ xb, const float* __restrict__ w13,
    const int* __restrict__ cnt, const int* __restrict__ off,
    const int* __restrict__ entry_mk, __hip_bfloat16* __restrict__ ACT) {
  __shared__ __align__(16) float lds[3 * 4 * 1024];   // 48 KB: buf x wave x 4KB
  int e = blockIdx.y;
  int ne = cnt[e];
  if (ne == 0) return;
  int base = off[e];
  int wv = threadIdx.x >> 6, lane = threadIdx.x & 63;
  int i0 = blockIdx.x * 64 + wv * 16;     // this wave's 16 gate cols
  int col = lane & 15, kq = lane >> 4;
  const float* w13e = w13 + (size_t)e * (2 * I_) * H_;

  // DMA sources: chunk q in {0,1}: gate rows i0+q*8+(lane>>3); {2,3}: up rows
  const float* dsrc[4];
#pragma unroll
  for (int q = 0; q < 4; ++q) {
    int r = (q & 1) * 8 + (lane >> 3);
    int j = (lane & 7) ^ ((lane >> 3) & 7);
    size_t row = (size_t)(i0 + r) + ((q >= 2) ? (size_t)I_ : (size_t)0);
    dsrc[q] = w13e + row * H_ + (size_t)(j * 4);
  }
  unsigned laneByte = (unsigned)((col * 8 + ((2 * kq) ^ (col & 7))) * 16);

  const int NCH = H_ / BKF;   // 64
  int ntile = (ne + 15) >> 4;
  for (int tb = 0; tb < ntile; tb += GT) {
    const __hip_bfloat16* arow0[GT];
#pragma unroll
    for (int t = 0; t < GT; ++t) {
      int p = (tb + t) * 16 + col;
      int pc = p < ne ? p : ne - 1;
      int tok = entry_mk[base + pc] >> 3;
      arow0[t] = xb + (size_t)tok * H_ + kq * 8;
    }
    f32x4 accg[GT], accu[GT];
#pragma unroll
    for (int t = 0; t < GT; ++t) {
      accg[t] = (f32x4){0.f, 0.f, 0.f, 0.f};
      accu[t] = (f32x4){0.f, 0.f, 0.f, 0.f};
    }
    bf16x8 aA[GT], aB[GT];
    int bc = 0;
    // prologue: DMA(0), A(0), DMA(1)
#pragma unroll
    for (int q = 0; q < 4; ++q) dma16(dsrc[q], &lds[(0 * 4 + wv) * 1024 + q * 256]);
    SB();
#pragma unroll
    for (int t = 0; t < GT; ++t) aA[t] = *reinterpret_cast<const bf16x8*>(arow0[t]);
    SB();
#pragma unroll
    for (int q = 0; q < 4; ++q) dma16(dsrc[q] + BKF, &lds[(1 * 4 + wv) * 1024 + q * 256]);
    SB();

    auto stepG = [&](int n, bf16x8 (&ac)[GT], bf16x8 (&an)[GT], int mode) {
      if (mode == 0) {                       // issue DMA(n+2)
        int bn = (bc == 0) ? 2 : bc - 1;     // (bc+2)%3
        size_t ko = (size_t)(n + 2) * BKF;
#pragma unroll
        for (int q = 0; q < 4; ++q)
          dma16(dsrc[q] + ko, &lds[(bn * 4 + wv) * 1024 + q * 256]);
        SB();
      }
      if (mode <= 1) {                       // issue A(n+1)
        size_t ka = (size_t)(n + 1) * BKF;
#pragma unroll
        for (int t = 0; t < GT; ++t)
          an[t] = *reinterpret_cast<const bf16x8*>(arow0[t] + ka);
        SB();
      }
      if (mode == 0)      asm volatile("s_waitcnt vmcnt(13)" ::: "memory");
      else if (mode == 1) asm volatile("s_waitcnt vmcnt(5)" ::: "memory");
      else                asm volatile("s_waitcnt vmcnt(0)" ::: "memory");
      SB();
      unsigned a0 = (unsigned)(size_t)(&lds[(bc * 4 + wv) * 1024]) + laneByte;
      unsigned a1 = a0 ^ 16u;
      f32x4 g0, g1, u0, u1;
      asm volatile("ds_read_b128 %0, %1" : "=v"(g0) : "v"(a0));
      asm volatile("ds_read_b128 %0, %1" : "=v"(g1) : "v"(a1));
      asm volatile("ds_read_b128 %0, %1 offset:2048" : "=v"(u0) : "v"(a0));
      asm volatile("ds_read_b128 %0, %1 offset:2048" : "=v"(u1) : "v"(a1));
      asm volatile("s_waitcnt lgkmcnt(0)" ::: "memory");
      SB();
      bf16x8 bg = packv(g0, g1);
      bf16x8 bu = packv(u0, u1);
#pragma unroll
      for (int t = 0; t < GT; ++t) {
        accg[t] = mfma16(ac[t], bg, accg[t]);
        accu[t] = mfma16(ac[t], bu, accu[t]);
      }
      bc = (bc == 2) ? 0 : bc + 1;
    };

#pragma unroll 1
    for (int n = 0; n + 2 < NCH; n += 2) {
      stepG(n, aA, aB, 0);
      stepG(n + 1, aB, aA, 0);
    }
    stepG(NCH - 2, aA, aB, 1);
    stepG(NCH - 1, aB, aA, 2);

    // epilogue: act = silu(g)*u -> bf16
#pragma unroll
    for (int t = 0; t < GT; ++t) {
#pragma unroll
      for (int r = 0; r < 4; ++r) {
        int m = (tb + t) * 16 + kq * 4 + r;
        if (m < ne) {
          float gv = accg[t][r], uv = accu[t][r];
          float act = gv / (1.f + __expf(-gv)) * uv;
          reinterpret_cast<unsigned short*>(ACT)[(size_t)(base + m) * I_ + i0 + col] =
              f2bfbits(act);
        }
      }
    }
  }
}

// ---------------- Down MFMA GEMM -> OUTS (fp32) ----------------
__global__ __launch_bounds__(256, 3) void down_mfma(
    const __hip_bfloat16* __restrict__ ACT, const float* __restrict__ w2,
    const int* __restrict__ cnt, const int* __restrict__ off,
    float* __restrict__ OUTS) {
  __shared__ __align__(16) float lds[3 * 4 * 512];    // 24 KB: buf x wave x 2KB
  int e = blockIdx.y;
  int ne = cnt[e];
  if (ne == 0) return;
  int base = off[e];
  int wv = threadIdx.x >> 6, lane = threadIdx.x & 63;
  int h0 = blockIdx.x * 64 + wv * 16;
  int col = lane & 15, kq = lane >> 4;
  const float* w2e = w2 + (size_t)e * H_ * I_;

  const float* dsrc[2];
#pragma unroll
  for (int q = 0; q < 2; ++q) {
    int r = q * 8 + (lane >> 3);
    int j = (lane & 7) ^ ((lane >> 3) & 7);
    dsrc[q] = w2e + (size_t)(h0 + r) * I_ + (size_t)(j * 4);
  }
  unsigned laneByte = (unsigned)((col * 8 + ((2 * kq) ^ (col & 7))) * 16);

  const int NCH = I_ / BKF;   // 24
  int ntile = (ne + 15) >> 4;
  for (int tb = 0; tb < ntile; tb += GT) {
    const __hip_bfloat16* arow0[GT];
#pragma unroll
    for (int t = 0; t < GT; ++t) {
      int p = (tb + t) * 16 + col;
      int pc = p < ne ? p : ne - 1;
      arow0[t] = ACT + (size_t)(base + pc) * I_ + kq * 8;
    }
    f32x4 acc[GT];
#pragma unroll
    for (int t = 0; t < GT; ++t) acc[t] = (f32x4){0.f, 0.f, 0.f, 0.f};
    bf16x8 aA[GT], aB[GT];
    int bc = 0;
#pragma unroll
    for (int q = 0; q < 2; ++q) dma16(dsrc[q], &lds[(0 * 4 + wv) * 512 + q * 256]);
    SB();
#pragma unroll
    for (int t = 0; t < GT; ++t) aA[t] = *reinterpret_cast<const bf16x8*>(arow0[t]);
    SB();
#pragma unroll
    for (int q = 0; q < 2; ++q) dma16(dsrc[q] + BKF, &lds[(1 * 4 + wv) * 512 + q * 256]);
    SB();

    auto stepD = [&](int n, bf16x8 (&ac)[GT], bf16x8 (&an)[GT], int mode) {
      if (mode == 0) {
        int bn = (bc == 0) ? 2 : bc - 1;
        size_t ko = (size_t)(n + 2) * BKF;
#pragma unroll
        for (int q = 0; q < 2; ++q)
          dma16(dsrc[q] + ko, &lds[(bn * 4 + wv) * 512 + q * 256]);
        SB();
      }
      if (mode <= 1) {
        size_t ka = (size_t)(n + 1) * BKF;
#pragma unroll
        for (int t = 0; t < GT; ++t)
          an[t] = *reinterpret_cast<const bf16x8*>(arow0[t] + ka);
        SB();
      }
      if (mode == 0)      asm volatile("s_waitcnt vmcnt(9)" ::: "memory");
      else if (mode == 1) asm volatile("s_waitcnt vmcnt(5)" ::: "memory");
      else                asm volatile("s_waitcnt vmcnt(0)" ::: "memory");
      SB();
      unsigned a0 = (unsigned)(size_t)(&lds[(bc * 4 + wv) * 512]) + laneByte;
      unsigned a1 = a0 ^ 16u;
      f32x4 w0, w1;
      asm volatile("ds_read_b128 %0, %1" : "=v"(w0) : "v"(a0));
      asm volatile("ds_read_b128 %0, %1" : "=v"(w1) : "v"(a1));
      asm volatile("s_waitcnt lgkmcnt(0)" ::: "memory");
      SB();
      bf16x8 bw = packv(w0, w1);
#pragma unroll
      for (int t = 0; t < GT; ++t) acc[t] = mfma16(ac[t], bw, acc[t]);
      bc = (bc == 2) ? 0 : bc + 1;
    };

#pragma unroll 1
    for (int n = 0; n + 2 < NCH; n += 2) {
      stepD(n, aA, aB, 0);
      stepD(n + 1, aB, aA, 0);
    }
    stepD(NCH - 2, aA, aB, 1);
    stepD(NCH - 1, aB, aA, 2);

#pragma unroll
    for (int t = 0; t < GT; ++t) {
#pragma unroll
      for (int r = 0; r < 4; ++r) {
        int m = (tb + t) * 16 + kq * 4 + r;
        if (m < ne) {
          OUTS[(size_t)(base + m) * H_ + h0 + col] = acc[t][r];
        }
      }
    }
  }
}

// ---------------- Weighted combine ----------------
__global__ __launch_bounds__(256) void combine_kernel(
    const float* __restrict__ OUTS, const float* __restrict__ topk_w,
    const int* __restrict__ slot2g, float* __restrict__ out) {
  int m = blockIdx.x;
  float w[K_]; int g[K_];
#pragma unroll
  for (int k = 0; k < K_; ++k) { w[k] = topk_w[m * K_ + k]; g[k] = slot2g[m * K_ + k]; }
  for (int h = threadIdx.x; h < H_; h += 256) {
    float s = 0.f;
#pragma unroll
    for (int k = 0; k < K_; ++k) s = fmaf(w[k], OUTS[(size_t)g[k] * H_ + h], s);
    out[(size_t)m * H_ + h] = s;
  }
}

extern "C" void kernel_launch(void* const* d_in, const int* in_sizes, int n_in,
                              void* d_out, int out_size, void* d_ws, size_t ws_size,
                              hipStream_t stream) {
  const float* x   = (const float*)d_in[0];
  const float* gw  = (const float*)d_in[1];
  const float* w13 = (const float*)d_in[2];
  const float* w2  = (const float*)d_in[3];
  float* out = (float*)d_out;

  const int M = in_sizes[0] / H_;   // 512
  const int MK = M * K_;            // 4096

  char* ws = (char*)d_ws;
  size_t o = 0;
  auto alloc = [&](size_t bytes) { size_t r = o; o = (o + bytes + 255) & ~(size_t)255; return r; };
  int*   topk_id  = (int*)(ws + alloc((size_t)MK * 4));
  float* topk_w   = (float*)(ws + alloc((size_t)MK * 4));
  int*   cnt      = (int*)(ws + alloc(E_ * 4));
  int*   off      = (int*)(ws + alloc((E_ + 1) * 4));
  int*   perEx    = (int*)(ws + alloc((size_t)E_ * M * 4));
  int*   entry_mk = (int*)(ws + alloc((size_t)MK * 4));
  int*   slot2g   = (int*)(ws + alloc((size_t)MK * 4));
  __hip_bfloat16* xb  = (__hip_bfloat16*)(ws + alloc((size_t)M * H_ * 2));
  __hip_bfloat16* ACT = (__hip_bfloat16*)(ws + alloc((size_t)MK * I_ * 2));
  float* OUTS     = (float*)(ws + alloc((size_t)MK * H_ * 4));
  (void)ws_size; (void)n_in; (void)out_size;

  router_kernel<<<M, 256, 0, stream>>>(x, gw, topk_id, topk_w, xb, cnt);
  scatter_kernel<<<(MK + 255) / 256, 256, 0, stream>>>(topk_id, cnt, perEx, MK, M);
  scan_kernel<<<1, 64, 0, stream>>>(cnt, off);
  compact_kernel<<<E_, 256, 0, stream>>>(cnt, off, perEx, entry_mk, slot2g, M);
  gateup_mfma<<<dim3(I_ / 64, E_), 256, 0, stream>>>(xb, w13, cnt, off, entry_mk, ACT);
  down_mfma<<<dim3(H_ / 64, E_), 256, 0, stream>>>(ACT, w2, cnt, off, OUTS);
  combine_kernel<<<M, 256, 0, stream>>>(OUTS, topk_w, slot2g, out);
}

// Round 6
// 455.448 us; speedup vs baseline: 3.9479x; 1.0298x over previous
//
#include <hip/hip_runtime.h>
#include <hip/hip_bf16.h>

#define H_ 2048
#define E_ 64
#define I_ 768
#define K_ 8
#define GT 5          // 16-row token tiles per pass (80 tokens)
#define BKF 32        // K-chunk in elements (128 B fp32 per row)

typedef __attribute__((ext_vector_type(8))) __bf16 bf16x8;
typedef __attribute__((ext_vector_type(4))) float f32x4;

__device__ inline unsigned short f2bfbits(float f) {
  unsigned u = __float_as_uint(f);
  u = (u + 0x7fffu + ((u >> 16) & 1u)) >> 16;   // RNE
  return (unsigned short)u;
}
__device__ inline f32x4 mfma16(bf16x8 a, bf16x8 b, f32x4 c) {
  return __builtin_amdgcn_mfma_f32_16x16x32_bf16(a, b, c, 0, 0, 0);
}
// v_cvt_pk_bf16_f32: RNE pack of 2 fp32 -> 2 bf16 in one dword
__device__ inline bf16x8 packv(f32x4 a, f32x4 b) {
  union { unsigned u[4]; bf16x8 v; } r;
  asm("v_cvt_pk_bf16_f32 %0, %1, %2" : "=v"(r.u[0]) : "v"(a[0]), "v"(a[1]));
  asm("v_cvt_pk_bf16_f32 %0, %1, %2" : "=v"(r.u[1]) : "v"(a[2]), "v"(a[3]));
  asm("v_cvt_pk_bf16_f32 %0, %1, %2" : "=v"(r.u[2]) : "v"(b[0]), "v"(b[1]));
  asm("v_cvt_pk_bf16_f32 %0, %1, %2" : "=v"(r.u[3]) : "v"(b[2]), "v"(b[3]));
  return r.v;
}
// async global->LDS, 16B/lane; LDS dest = wave-uniform base + lane*16 (implicit)
__device__ inline void dma16(const float* g, float* l) {
  __builtin_amdgcn_global_load_lds(
      (const __attribute__((address_space(1))) float*)g,
      (__attribute__((address_space(3))) float*)l, 16, 0, 0);
}
#define SB() __builtin_amdgcn_sched_barrier(0)

// ---------------- Router (fp32-exact) + fused x->bf16 cast + cnt zero --------
__global__ __launch_bounds__(256) void router_kernel(
    const float* __restrict__ x, const float* __restrict__ gw,
    int* __restrict__ topk_id, float* __restrict__ topk_w,
    __hip_bfloat16* __restrict__ xb, int* __restrict__ cnt) {
  __shared__ float xs[H_];
  __shared__ float probs[E_];
  int m = blockIdx.x;
  if (m == 0 && threadIdx.x < E_) cnt[threadIdx.x] = 0;
  const float* xr = x + (size_t)m * H_;
  for (int i = threadIdx.x; i < H_; i += 256) xs[i] = xr[i];
  __syncthreads();
  unsigned short* xbr = reinterpret_cast<unsigned short*>(xb) + (size_t)m * H_;
  for (int i = threadIdx.x; i < H_; i += 256) xbr[i] = f2bfbits(xs[i]);
  int e = threadIdx.x >> 2, part = threadIdx.x & 3;
  const float* gr = gw + (size_t)e * H_ + part * (H_ / 4);
  const float* xx = xs + part * (H_ / 4);
  float s = 0.f;
#pragma unroll 8
  for (int i = 0; i < H_ / 4; ++i) s = fmaf(xx[i], gr[i], s);
  s += __shfl_xor(s, 1);
  s += __shfl_xor(s, 2);
  if (part == 0) probs[e] = s;
  __syncthreads();
  if (threadIdx.x == 0) {
    float mx = -1e30f;
    for (int i = 0; i < E_; ++i) mx = fmaxf(mx, probs[i]);
    float sum = 0.f;
    for (int i = 0; i < E_; ++i) { float p = expf(probs[i] - mx); probs[i] = p; sum += p; }
    float inv = 1.f / sum;
    for (int i = 0; i < E_; ++i) probs[i] *= inv;
    float bw[K_]; int bi[K_]; float wsum = 0.f;
#pragma unroll
    for (int k = 0; k < K_; ++k) {
      float best = -1.f; int b = 0;
      for (int i = 0; i < E_; ++i) if (probs[i] > best) { best = probs[i]; b = i; }
      bw[k] = best; bi[k] = b; wsum += best; probs[b] = -2.f;
    }
    float winv = 1.f / wsum;
#pragma unroll
    for (int k = 0; k < K_; ++k) {
      topk_id[m * K_ + k] = bi[k];
      topk_w[m * K_ + k] = bw[k] * winv;
    }
  }
}

// ---------------- Expert list build ----------------
__global__ void scatter_kernel(const int* __restrict__ topk_id, int* cnt,
                               int* perEx, int MK, int M) {
  int idx = blockIdx.x * 256 + threadIdx.x;
  if (idx >= MK) return;
  int e = topk_id[idx];
  int pos = atomicAdd(cnt + e, 1);
  perEx[e * M + pos] = idx;  // idx == m*K_+k
}

__global__ void scan_kernel(const int* cnt, int* off) {
  if (threadIdx.x == 0) {
    int a = 0;
    for (int e = 0; e < E_; ++e) { off[e] = a; a += cnt[e]; }
    off[E_] = a;
  }
}

__global__ void compact_kernel(const int* __restrict__ cnt, const int* __restrict__ off,
                               const int* __restrict__ perEx,
                               int* __restrict__ entry_mk, int* __restrict__ slot2g, int M) {
  int e = blockIdx.x; int n = cnt[e]; int b = off[e];
  for (int p = threadIdx.x; p < n; p += 256) {
    int mk = perEx[e * M + p];
    entry_mk[b + p] = mk;
    slot2g[mk] = b + p;
  }
}

// ---------------- Gate/Up MFMA GEMM + SiLU -> ACT (bf16) ----------------
// Wave-private LDS triple-buffer, TRUE depth-2 DMA prefetch (A issued before
// DMA so the in-order vmcnt drain releases exactly DMA(n)+A(n)), no barriers.
__global__ __launch_bounds__(256, 3) void gateup_mfma(
    const __hip_bfloat16* __restrict__ xb, const float* __restrict__ w13,
    const int* __restrict__ cnt, const int* __restrict__ off,
    const int* __restrict__ entry_mk, __hip_bfloat16* __restrict__ ACT) {
  __shared__ __align__(16) float lds[3 * 4 * 1024];   // 48 KB: buf x wave x 4KB
  int e = blockIdx.y;
  int ne = cnt[e];
  if (ne == 0) return;
  int base = off[e];
  int wv = threadIdx.x >> 6, lane = threadIdx.x & 63;
  int i0 = blockIdx.x * 64 + wv * 16;     // this wave's 16 gate cols
  int col = lane & 15, kq = lane >> 4;
  const float* w13e = w13 + (size_t)e * (2 * I_) * H_;

  // DMA sources: chunk q in {0,1}: gate rows i0+q*8+(lane>>3); {2,3}: up rows
  const float* dsrc[4];
#pragma unroll
  for (int q = 0; q < 4; ++q) {
    int r = (q & 1) * 8 + (lane >> 3);
    int j = (lane & 7) ^ ((lane >> 3) & 7);
    size_t row = (size_t)(i0 + r) + ((q >= 2) ? (size_t)I_ : (size_t)0);
    dsrc[q] = w13e + row * H_ + (size_t)(j * 4);
  }
  unsigned laneByte = (unsigned)((col * 8 + ((2 * kq) ^ (col & 7))) * 16);

  const int NCH = H_ / BKF;   // 64
  int ntile = (ne + 15) >> 4;
  for (int tb = 0; tb < ntile; tb += GT) {
    const __hip_bfloat16* arow0[GT];
#pragma unroll
    for (int t = 0; t < GT; ++t) {
      int p = (tb + t) * 16 + col;
      int pc = p < ne ? p : ne - 1;
      int tok = entry_mk[base + pc] >> 3;
      arow0[t] = xb + (size_t)tok * H_ + kq * 8;
    }
    f32x4 accg[GT], accu[GT];
#pragma unroll
    for (int t = 0; t < GT; ++t) {
      accg[t] = (f32x4){0.f, 0.f, 0.f, 0.f};
      accu[t] = (f32x4){0.f, 0.f, 0.f, 0.f};
    }
    bf16x8 aA[GT], aB[GT];
    int bc = 0;
    // prologue: DMA(0), A(0), DMA(1)
#pragma unroll
    for (int q = 0; q < 4; ++q) dma16(dsrc[q], &lds[(0 * 4 + wv) * 1024 + q * 256]);
    SB();
#pragma unroll
    for (int t = 0; t < GT; ++t) aA[t] = *reinterpret_cast<const bf16x8*>(arow0[t]);
    SB();
#pragma unroll
    for (int q = 0; q < 4; ++q) dma16(dsrc[q] + BKF, &lds[(1 * 4 + wv) * 1024 + q * 256]);
    SB();

    auto stepG = [&](int n, bf16x8 (&ac)[GT], bf16x8 (&an)[GT], int mode) {
      if (mode <= 1) {                       // issue A(n+1) FIRST
        size_t ka = (size_t)(n + 1) * BKF;
#pragma unroll
        for (int t = 0; t < GT; ++t)
          an[t] = *reinterpret_cast<const bf16x8*>(arow0[t] + ka);
        SB();
      }
      if (mode == 0) {                       // then DMA(n+2)
        int bn = (bc == 0) ? 2 : bc - 1;     // (bc+2)%3
        size_t ko = (size_t)(n + 2) * BKF;
#pragma unroll
        for (int q = 0; q < 4; ++q)
          dma16(dsrc[q] + ko, &lds[(bn * 4 + wv) * 1024 + q * 256]);
        SB();
      }
      // oldest->newest: DMA(n),A(n),DMA(n+1),A(n+1),DMA(n+2); drain DMA(n)+A(n)
      if (mode == 0)      asm volatile("s_waitcnt vmcnt(13)" ::: "memory");
      else if (mode == 1) asm volatile("s_waitcnt vmcnt(9)" ::: "memory");
      else                asm volatile("s_waitcnt vmcnt(0)" ::: "memory");
      SB();
      unsigned a0 = (unsigned)(size_t)(&lds[(bc * 4 + wv) * 1024]) + laneByte;
      unsigned a1 = a0 ^ 16u;
      f32x4 g0, g1, u0, u1;
      asm volatile("ds_read_b128 %0, %1" : "=v"(g0) : "v"(a0));
      asm volatile("ds_read_b128 %0, %1" : "=v"(g1) : "v"(a1));
      asm volatile("ds_read_b128 %0, %1 offset:2048" : "=v"(u0) : "v"(a0));
      asm volatile("ds_read_b128 %0, %1 offset:2048" : "=v"(u1) : "v"(a1));
      asm volatile("s_waitcnt lgkmcnt(0)" ::: "memory");
      SB();
      bf16x8 bg = packv(g0, g1);
      bf16x8 bu = packv(u0, u1);
#pragma unroll
      for (int t = 0; t < GT; ++t) {
        accg[t] = mfma16(ac[t], bg, accg[t]);
        accu[t] = mfma16(ac[t], bu, accu[t]);
      }
      bc = (bc == 2) ? 0 : bc + 1;
    };

#pragma unroll 1
    for (int n = 0; n + 2 < NCH; n += 2) {
      stepG(n, aA, aB, 0);
      stepG(n + 1, aB, aA, 0);
    }
    stepG(NCH - 2, aA, aB, 1);
    stepG(NCH - 1, aB, aA, 2);

    // epilogue: act = silu(g)*u -> bf16
#pragma unroll
    for (int t = 0; t < GT; ++t) {
#pragma unroll
      for (int r = 0; r < 4; ++r) {
        int m = (tb + t) * 16 + kq * 4 + r;
        if (m < ne) {
          float gv = accg[t][r], uv = accu[t][r];
          float act = gv / (1.f + __expf(-gv)) * uv;
          reinterpret_cast<unsigned short*>(ACT)[(size_t)(base + m) * I_ + i0 + col] =
              f2bfbits(act);
        }
      }
    }
  }
}

// ---------------- Down MFMA GEMM -> OUTS (fp32) ----------------
__global__ __launch_bounds__(256, 3) void down_mfma(
    const __hip_bfloat16* __restrict__ ACT, const float* __restrict__ w2,
    const int* __restrict__ cnt, const int* __restrict__ off,
    float* __restrict__ OUTS) {
  __shared__ __align__(16) float lds[3 * 4 * 512];    // 24 KB: buf x wave x 2KB
  int e = blockIdx.y;
  int ne = cnt[e];
  if (ne == 0) return;
  int base = off[e];
  int wv = threadIdx.x >> 6, lane = threadIdx.x & 63;
  int h0 = blockIdx.x * 64 + wv * 16;
  int col = lane & 15, kq = lane >> 4;
  const float* w2e = w2 + (size_t)e * H_ * I_;

  const float* dsrc[2];
#pragma unroll
  for (int q = 0; q < 2; ++q) {
    int r = q * 8 + (lane >> 3);
    int j = (lane & 7) ^ ((lane >> 3) & 7);
    dsrc[q] = w2e + (size_t)(h0 + r) * I_ + (size_t)(j * 4);
  }
  unsigned laneByte = (unsigned)((col * 8 + ((2 * kq) ^ (col & 7))) * 16);

  const int NCH = I_ / BKF;   // 24
  int ntile = (ne + 15) >> 4;
  for (int tb = 0; tb < ntile; tb += GT) {
    const __hip_bfloat16* arow0[GT];
#pragma unroll
    for (int t = 0; t < GT; ++t) {
      int p = (tb + t) * 16 + col;
      int pc = p < ne ? p : ne - 1;
      arow0[t] = ACT + (size_t)(base + pc) * I_ + kq * 8;
    }
    f32x4 acc[GT];
#pragma unroll
    for (int t = 0; t < GT; ++t) acc[t] = (f32x4){0.f, 0.f, 0.f, 0.f};
    bf16x8 aA[GT], aB[GT];
    int bc = 0;
#pragma unroll
    for (int q = 0; q < 2; ++q) dma16(dsrc[q], &lds[(0 * 4 + wv) * 512 + q * 256]);
    SB();
#pragma unroll
    for (int t = 0; t < GT; ++t) aA[t] = *reinterpret_cast<const bf16x8*>(arow0[t]);
    SB();
#pragma unroll
    for (int q = 0; q < 2; ++q) dma16(dsrc[q] + BKF, &lds[(1 * 4 + wv) * 512 + q * 256]);
    SB();

    auto stepD = [&](int n, bf16x8 (&ac)[GT], bf16x8 (&an)[GT], int mode) {
      if (mode <= 1) {                       // A(n+1) first
        size_t ka = (size_t)(n + 1) * BKF;
#pragma unroll
        for (int t = 0; t < GT; ++t)
          an[t] = *reinterpret_cast<const bf16x8*>(arow0[t] + ka);
        SB();
      }
      if (mode == 0) {                       // then DMA(n+2)
        int bn = (bc == 0) ? 2 : bc - 1;
        size_t ko = (size_t)(n + 2) * BKF;
#pragma unroll
        for (int q = 0; q < 2; ++q)
          dma16(dsrc[q] + ko, &lds[(bn * 4 + wv) * 512 + q * 256]);
        SB();
      }
      if (mode == 0)      asm volatile("s_waitcnt vmcnt(9)" ::: "memory");
      else if (mode == 1) asm volatile("s_waitcnt vmcnt(7)" ::: "memory");
      else                asm volatile("s_waitcnt vmcnt(0)" ::: "memory");
      SB();
      unsigned a0 = (unsigned)(size_t)(&lds[(bc * 4 + wv) * 512]) + laneByte;
      unsigned a1 = a0 ^ 16u;
      f32x4 w0, w1;
      asm volatile("ds_read_b128 %0, %1" : "=v"(w0) : "v"(a0));
      asm volatile("ds_read_b128 %0, %1" : "=v"(w1) : "v"(a1));
      asm volatile("s_waitcnt lgkmcnt(0)" ::: "memory");
      SB();
      bf16x8 bw = packv(w0, w1);
#pragma unroll
      for (int t = 0; t < GT; ++t) acc[t] = mfma16(ac[t], bw, acc[t]);
      bc = (bc == 2) ? 0 : bc + 1;
    };

#pragma unroll 1
    for (int n = 0; n + 2 < NCH; n += 2) {
      stepD(n, aA, aB, 0);
      stepD(n + 1, aB, aA, 0);
    }
    stepD(NCH - 2, aA, aB, 1);
    stepD(NCH - 1, aB, aA, 2);

#pragma unroll
    for (int t = 0; t < GT; ++t) {
#pragma unroll
      for (int r = 0; r < 4; ++r) {
        int m = (tb + t) * 16 + kq * 4 + r;
        if (m < ne) {
          OUTS[(size_t)(base + m) * H_ + h0 + col] = acc[t][r];
        }
      }
    }
  }
}

// ---------------- Weighted combine ----------------
__global__ __launch_bounds__(256) void combine_kernel(
    const float* __restrict__ OUTS, const float* __restrict__ topk_w,
    const int* __restrict__ slot2g, float* __restrict__ out) {
  int m = blockIdx.x;
  float w[K_]; int g[K_];
#pragma unroll
  for (int k = 0; k < K_; ++k) { w[k] = topk_w[m * K_ + k]; g[k] = slot2g[m * K_ + k]; }
  for (int h = threadIdx.x; h < H_; h += 256) {
    float s = 0.f;
#pragma unroll
    for (int k = 0; k < K_; ++k) s = fmaf(w[k], OUTS[(size_t)g[k] * H_ + h], s);
    out[(size_t)m * H_ + h] = s;
  }
}

extern "C" void kernel_launch(void* const* d_in, const int* in_sizes, int n_in,
                              void* d_out, int out_size, void* d_ws, size_t ws_size,
                              hipStream_t stream) {
  const float* x   = (const float*)d_in[0];
  const float* gw  = (const float*)d_in[1];
  const float* w13 = (const float*)d_in[2];
  const float* w2  = (const float*)d_in[3];
  float* out = (float*)d_out;

  const int M = in_sizes[0] / H_;   // 512
  const int MK = M * K_;            // 4096

  char* ws = (char*)d_ws;
  size_t o = 0;
  auto alloc = [&](size_t bytes) { size_t r = o; o = (o + bytes + 255) & ~(size_t)255; return r; };
  int*   topk_id  = (int*)(ws + alloc((size_t)MK * 4));
  float* topk_w   = (float*)(ws + alloc((size_t)MK * 4));
  int*   cnt      = (int*)(ws + alloc(E_ * 4));
  int*   off      = (int*)(ws + alloc((E_ + 1) * 4));
  int*   perEx    = (int*)(ws + alloc((size_t)E_ * M * 4));
  int*   entry_mk = (int*)(ws + alloc((size_t)MK * 4));
  int*   slot2g   = (int*)(ws + alloc((size_t)MK * 4));
  __hip_bfloat16* xb  = (__hip_bfloat16*)(ws + alloc((size_t)M * H_ * 2));
  __hip_bfloat16* ACT = (__hip_bfloat16*)(ws + alloc((size_t)MK * I_ * 2));
  float* OUTS     = (float*)(ws + alloc((size_t)MK * H_ * 4));
  (void)ws_size; (void)n_in; (void)out_size;

  router_kernel<<<M, 256, 0, stream>>>(x, gw, topk_id, topk_w, xb, cnt);
  scatter_kernel<<<(MK + 255) / 256, 256, 0, stream>>>(topk_id, cnt, perEx, MK, M);
  scan_kernel<<<1, 64, 0, stream>>>(cnt, off);
  compact_kernel<<<E_, 256, 0, stream>>>(cnt, off, perEx, entry_mk, slot2g, M);
  gateup_mfma<<<dim3(I_ / 64, E_), 256, 0, stream>>>(xb, w13, cnt, off, entry_mk, ACT);
  down_mfma<<<dim3(H_ / 64, E_), 256, 0, stream>>>(ACT, w2, cnt, off, OUTS);
  combine_kernel<<<M, 256, 0, stream>>>(OUTS, topk_w, slot2g, out);
}

// Round 7
// 447.797 us; speedup vs baseline: 4.0154x; 1.0171x over previous
//
#include <hip/hip_runtime.h>
#include <hip/hip_bf16.h>

#define H_ 2048
#define E_ 64
#define I_ 768
#define K_ 8
#define GT 6          // 16-row token tiles per pass (96 tokens)
#define BKF 32        // K-chunk in elements (128 B fp32 per row)

typedef __attribute__((ext_vector_type(8))) __bf16 bf16x8;
typedef __attribute__((ext_vector_type(4))) float f32x4;

__device__ inline unsigned short f2bfbits(float f) {
  unsigned u = __float_as_uint(f);
  u = (u + 0x7fffu + ((u >> 16) & 1u)) >> 16;   // RNE
  return (unsigned short)u;
}
__device__ inline f32x4 mfma16(bf16x8 a, bf16x8 b, f32x4 c) {
  return __builtin_amdgcn_mfma_f32_16x16x32_bf16(a, b, c, 0, 0, 0);
}
// v_cvt_pk_bf16_f32: RNE pack of 2 fp32 -> 2 bf16 in one dword
__device__ inline bf16x8 packv(f32x4 a, f32x4 b) {
  union { unsigned u[4]; bf16x8 v; } r;
  asm("v_cvt_pk_bf16_f32 %0, %1, %2" : "=v"(r.u[0]) : "v"(a[0]), "v"(a[1]));
  asm("v_cvt_pk_bf16_f32 %0, %1, %2" : "=v"(r.u[1]) : "v"(a[2]), "v"(a[3]));
  asm("v_cvt_pk_bf16_f32 %0, %1, %2" : "=v"(r.u[2]) : "v"(b[0]), "v"(b[1]));
  asm("v_cvt_pk_bf16_f32 %0, %1, %2" : "=v"(r.u[3]) : "v"(b[2]), "v"(b[3]));
  return r.v;
}
// async global->LDS, 16B/lane; LDS dest = wave-uniform base + lane*16 (implicit)
__device__ inline void dma16(const float* g, float* l) {
  __builtin_amdgcn_global_load_lds(
      (const __attribute__((address_space(1))) float*)g,
      (__attribute__((address_space(3))) float*)l, 16, 0, 0);
}
#define SB() __builtin_amdgcn_sched_barrier(0)

// ---------------- Router (fp32-exact) + fused x->bf16 cast + cnt zero --------
__global__ __launch_bounds__(256) void router_kernel(
    const float* __restrict__ x, const float* __restrict__ gw,
    int* __restrict__ topk_id, float* __restrict__ topk_w,
    __hip_bfloat16* __restrict__ xb, int* __restrict__ cnt) {
  __shared__ float xs[H_];
  __shared__ float probs[E_];
  int m = blockIdx.x;
  if (m == 0 && threadIdx.x < E_) cnt[threadIdx.x] = 0;
  const float* xr = x + (size_t)m * H_;
  for (int i = threadIdx.x; i < H_; i += 256) xs[i] = xr[i];
  __syncthreads();
  unsigned short* xbr = reinterpret_cast<unsigned short*>(xb) + (size_t)m * H_;
  for (int i = threadIdx.x; i < H_; i += 256) xbr[i] = f2bfbits(xs[i]);
  int e = threadIdx.x >> 2, part = threadIdx.x & 3;
  const float* gr = gw + (size_t)e * H_ + part * (H_ / 4);
  const float* xx = xs + part * (H_ / 4);
  float s = 0.f;
#pragma unroll 8
  for (int i = 0; i < H_ / 4; ++i) s = fmaf(xx[i], gr[i], s);
  s += __shfl_xor(s, 1);
  s += __shfl_xor(s, 2);
  if (part == 0) probs[e] = s;
  __syncthreads();
  if (threadIdx.x == 0) {
    float mx = -1e30f;
    for (int i = 0; i < E_; ++i) mx = fmaxf(mx, probs[i]);
    float sum = 0.f;
    for (int i = 0; i < E_; ++i) { float p = expf(probs[i] - mx); probs[i] = p; sum += p; }
    float inv = 1.f / sum;
    for (int i = 0; i < E_; ++i) probs[i] *= inv;
    float bw[K_]; int bi[K_]; float wsum = 0.f;
#pragma unroll
    for (int k = 0; k < K_; ++k) {
      float best = -1.f; int b = 0;
      for (int i = 0; i < E_; ++i) if (probs[i] > best) { best = probs[i]; b = i; }
      bw[k] = best; bi[k] = b; wsum += best; probs[b] = -2.f;
    }
    float winv = 1.f / wsum;
#pragma unroll
    for (int k = 0; k < K_; ++k) {
      topk_id[m * K_ + k] = bi[k];
      topk_w[m * K_ + k] = bw[k] * winv;
    }
  }
}

// ---------------- Expert list build ----------------
__global__ void scatter_kernel(const int* __restrict__ topk_id, int* cnt,
                               int* perEx, int MK, int M) {
  int idx = blockIdx.x * 256 + threadIdx.x;
  if (idx >= MK) return;
  int e = topk_id[idx];
  int pos = atomicAdd(cnt + e, 1);
  perEx[e * M + pos] = idx;  // idx == m*K_+k
}

__global__ void scan_kernel(const int* cnt, int* off) {
  if (threadIdx.x == 0) {
    int a = 0;
    for (int e = 0; e < E_; ++e) { off[e] = a; a += cnt[e]; }
    off[E_] = a;
  }
}

__global__ void compact_kernel(const int* __restrict__ cnt, const int* __restrict__ off,
                               const int* __restrict__ perEx,
                               int* __restrict__ entry_mk, int* __restrict__ slot2g, int M) {
  int e = blockIdx.x; int n = cnt[e]; int b = off[e];
  for (int p = threadIdx.x; p < n; p += 256) {
    int mk = perEx[e * M + p];
    entry_mk[b + p] = mk;
    slot2g[mk] = b + p;
  }
}

// ---------------- Gate/Up MFMA GEMM + SiLU -> ACT (bf16) ----------------
// Wave-private LDS triple-buffer, depth-2 DMA prefetch, no barriers.
// K-loop starts at a per-(block,wave) rotated chunk to decorrelate the low
// address bits (HBM channel / DRAM-row spread) of the 8KB-strided weight rows.
__global__ __launch_bounds__(256, 3) void gateup_mfma(
    const __hip_bfloat16* __restrict__ xb, const float* __restrict__ w13,
    const int* __restrict__ cnt, const int* __restrict__ off,
    const int* __restrict__ entry_mk, __hip_bfloat16* __restrict__ ACT) {
  __shared__ __align__(16) float lds[3 * 4 * 1024];   // 48 KB: buf x wave x 4KB
  int e = blockIdx.y;
  int ne = cnt[e];
  if (ne == 0) return;
  int base = off[e];
  int wv = threadIdx.x >> 6, lane = threadIdx.x & 63;
  int i0 = blockIdx.x * 64 + wv * 16;     // this wave's 16 gate cols
  int col = lane & 15, kq = lane >> 4;
  const float* w13e = w13 + (size_t)e * (2 * I_) * H_;

  const int NCH = H_ / BKF;   // 64
  int st = (((blockIdx.x * 4 + wv) + blockIdx.y * 13) * 7) & (NCH - 1);

  // DMA sources: chunk q in {0,1}: gate rows i0+q*8+(lane>>3); {2,3}: up rows
  const float* dsrc[4];
#pragma unroll
  for (int q = 0; q < 4; ++q) {
    int r = (q & 1) * 8 + (lane >> 3);
    int j = (lane & 7) ^ ((lane >> 3) & 7);
    size_t row = (size_t)(i0 + r) + ((q >= 2) ? (size_t)I_ : (size_t)0);
    dsrc[q] = w13e + row * H_ + (size_t)(j * 4);
  }
  unsigned laneByte = (unsigned)((col * 8 + ((2 * kq) ^ (col & 7))) * 16);

  int ntile = (ne + 15) >> 4;
  for (int tb = 0; tb < ntile; tb += GT) {
    const __hip_bfloat16* arow0[GT];
#pragma unroll
    for (int t = 0; t < GT; ++t) {
      int p = (tb + t) * 16 + col;
      int pc = p < ne ? p : ne - 1;
      int tok = entry_mk[base + pc] >> 3;
      arow0[t] = xb + (size_t)tok * H_ + kq * 8;
    }
    f32x4 accg[GT], accu[GT];
#pragma unroll
    for (int t = 0; t < GT; ++t) {
      accg[t] = (f32x4){0.f, 0.f, 0.f, 0.f};
      accu[t] = (f32x4){0.f, 0.f, 0.f, 0.f};
    }
    bf16x8 aA[GT], aB[GT];
    int bc = 0;
    auto ch = [&](int n) { int c = st + n; if (c >= NCH) c -= NCH; return c; };
    // prologue: DMA(c0), A(c0), DMA(c1)
    {
      size_t k0 = (size_t)ch(0) * BKF;
#pragma unroll
      for (int q = 0; q < 4; ++q) dma16(dsrc[q] + k0, &lds[(0 * 4 + wv) * 1024 + q * 256]);
      SB();
#pragma unroll
      for (int t = 0; t < GT; ++t) aA[t] = *reinterpret_cast<const bf16x8*>(arow0[t] + k0);
      SB();
      size_t k1 = (size_t)ch(1) * BKF;
#pragma unroll
      for (int q = 0; q < 4; ++q) dma16(dsrc[q] + k1, &lds[(1 * 4 + wv) * 1024 + q * 256]);
      SB();
    }

    auto stepG = [&](int n, bf16x8 (&ac)[GT], bf16x8 (&an)[GT], int mode) {
      if (mode <= 1) {                       // issue A(n+1) FIRST
        size_t ka = (size_t)ch(n + 1) * BKF;
#pragma unroll
        for (int t = 0; t < GT; ++t)
          an[t] = *reinterpret_cast<const bf16x8*>(arow0[t] + ka);
        SB();
      }
      if (mode == 0) {                       // then DMA(n+2)
        int bn = (bc == 0) ? 2 : bc - 1;     // (bc+2)%3
        size_t ko = (size_t)ch(n + 2) * BKF;
#pragma unroll
        for (int q = 0; q < 4; ++q)
          dma16(dsrc[q] + ko, &lds[(bn * 4 + wv) * 1024 + q * 256]);
        SB();
      }
      // oldest->newest: DMA(n)4,A(n)6,DMA(n+1)4,A(n+1)6,DMA(n+2)4; drain DMA(n)+A(n)
      if (mode == 0)      asm volatile("s_waitcnt vmcnt(14)" ::: "memory");
      else if (mode == 1) asm volatile("s_waitcnt vmcnt(10)" ::: "memory");
      else                asm volatile("s_waitcnt vmcnt(0)" ::: "memory");
      SB();
      unsigned a0 = (unsigned)(size_t)(&lds[(bc * 4 + wv) * 1024]) + laneByte;
      unsigned a1 = a0 ^ 16u;
      f32x4 g0, g1, u0, u1;
      asm volatile("ds_read_b128 %0, %1" : "=v"(g0) : "v"(a0));
      asm volatile("ds_read_b128 %0, %1" : "=v"(g1) : "v"(a1));
      asm volatile("ds_read_b128 %0, %1 offset:2048" : "=v"(u0) : "v"(a0));
      asm volatile("ds_read_b128 %0, %1 offset:2048" : "=v"(u1) : "v"(a1));
      asm volatile("s_waitcnt lgkmcnt(0)" ::: "memory");
      SB();
      bf16x8 bg = packv(g0, g1);
      bf16x8 bu = packv(u0, u1);
#pragma unroll
      for (int t = 0; t < GT; ++t) {
        accg[t] = mfma16(ac[t], bg, accg[t]);
        accu[t] = mfma16(ac[t], bu, accu[t]);
      }
      bc = (bc == 2) ? 0 : bc + 1;
    };

#pragma unroll 1
    for (int n = 0; n + 2 < NCH; n += 2) {
      stepG(n, aA, aB, 0);
      stepG(n + 1, aB, aA, 0);
    }
    stepG(NCH - 2, aA, aB, 1);
    stepG(NCH - 1, aB, aA, 2);

    // epilogue: act = silu(g)*u -> bf16
#pragma unroll
    for (int t = 0; t < GT; ++t) {
#pragma unroll
      for (int r = 0; r < 4; ++r) {
        int m = (tb + t) * 16 + kq * 4 + r;
        if (m < ne) {
          float gv = accg[t][r], uv = accu[t][r];
          float act = gv / (1.f + __expf(-gv)) * uv;
          reinterpret_cast<unsigned short*>(ACT)[(size_t)(base + m) * I_ + i0 + col] =
              f2bfbits(act);
        }
      }
    }
  }
}

// ---------------- Down MFMA GEMM -> OUTS (fp32) ----------------
__global__ __launch_bounds__(256, 3) void down_mfma(
    const __hip_bfloat16* __restrict__ ACT, const float* __restrict__ w2,
    const int* __restrict__ cnt, const int* __restrict__ off,
    float* __restrict__ OUTS) {
  __shared__ __align__(16) float lds[3 * 4 * 512];    // 24 KB: buf x wave x 2KB
  int e = blockIdx.y;
  int ne = cnt[e];
  if (ne == 0) return;
  int base = off[e];
  int wv = threadIdx.x >> 6, lane = threadIdx.x & 63;
  int h0 = blockIdx.x * 64 + wv * 16;
  int col = lane & 15, kq = lane >> 4;
  const float* w2e = w2 + (size_t)e * H_ * I_;

  const int NCH = I_ / BKF;   // 24
  int st = (unsigned)(((blockIdx.x * 4 + wv) + blockIdx.y * 13) * 7) % (unsigned)NCH;

  const float* dsrc[2];
#pragma unroll
  for (int q = 0; q < 2; ++q) {
    int r = q * 8 + (lane >> 3);
    int j = (lane & 7) ^ ((lane >> 3) & 7);
    dsrc[q] = w2e + (size_t)(h0 + r) * I_ + (size_t)(j * 4);
  }
  unsigned laneByte = (unsigned)((col * 8 + ((2 * kq) ^ (col & 7))) * 16);

  int ntile = (ne + 15) >> 4;
  for (int tb = 0; tb < ntile; tb += GT) {
    const __hip_bfloat16* arow0[GT];
#pragma unroll
    for (int t = 0; t < GT; ++t) {
      int p = (tb + t) * 16 + col;
      int pc = p < ne ? p : ne - 1;
      arow0[t] = ACT + (size_t)(base + pc) * I_ + kq * 8;
    }
    f32x4 acc[GT];
#pragma unroll
    for (int t = 0; t < GT; ++t) acc[t] = (f32x4){0.f, 0.f, 0.f, 0.f};
    bf16x8 aA[GT], aB[GT];
    int bc = 0;
    auto ch = [&](int n) { int c = st + n; if (c >= NCH) c -= NCH; return c; };
    {
      size_t k0 = (size_t)ch(0) * BKF;
#pragma unroll
      for (int q = 0; q < 2; ++q) dma16(dsrc[q] + k0, &lds[(0 * 4 + wv) * 512 + q * 256]);
      SB();
#pragma unroll
      for (int t = 0; t < GT; ++t) aA[t] = *reinterpret_cast<const bf16x8*>(arow0[t] + k0);
      SB();
      size_t k1 = (size_t)ch(1) * BKF;
#pragma unroll
      for (int q = 0; q < 2; ++q) dma16(dsrc[q] + k1, &lds[(1 * 4 + wv) * 512 + q * 256]);
      SB();
    }

    auto stepD = [&](int n, bf16x8 (&ac)[GT], bf16x8 (&an)[GT], int mode) {
      if (mode <= 1) {                       // A(n+1) first
        size_t ka = (size_t)ch(n + 1) * BKF;
#pragma unroll
        for (int t = 0; t < GT; ++t)
          an[t] = *reinterpret_cast<const bf16x8*>(arow0[t] + ka);
        SB();
      }
      if (mode == 0) {                       // then DMA(n+2)
        int bn = (bc == 0) ? 2 : bc - 1;
        size_t ko = (size_t)ch(n + 2) * BKF;
#pragma unroll
        for (int q = 0; q < 2; ++q)
          dma16(dsrc[q] + ko, &lds[(bn * 4 + wv) * 512 + q * 256]);
        SB();
      }
      // oldest->newest: DMA(n)2,A(n)6,DMA(n+1)2,A(n+1)6,DMA(n+2)2
      if (mode == 0)      asm volatile("s_waitcnt vmcnt(10)" ::: "memory");
      else if (mode == 1) asm volatile("s_waitcnt vmcnt(8)" ::: "memory");
      else                asm volatile("s_waitcnt vmcnt(0)" ::: "memory");
      SB();
      unsigned a0 = (unsigned)(size_t)(&lds[(bc * 4 + wv) * 512]) + laneByte;
      unsigned a1 = a0 ^ 16u;
      f32x4 w0, w1;
      asm volatile("ds_read_b128 %0, %1" : "=v"(w0) : "v"(a0));
      asm volatile("ds_read_b128 %0, %1" : "=v"(w1) : "v"(a1));
      asm volatile("s_waitcnt lgkmcnt(0)" ::: "memory");
      SB();
      bf16x8 bw = packv(w0, w1);
#pragma unroll
      for (int t = 0; t < GT; ++t) acc[t] = mfma16(ac[t], bw, acc[t]);
      bc = (bc == 2) ? 0 : bc + 1;
    };

#pragma unroll 1
    for (int n = 0; n + 2 < NCH; n += 2) {
      stepD(n, aA, aB, 0);
      stepD(n + 1, aB, aA, 0);
    }
    stepD(NCH - 2, aA, aB, 1);
    stepD(NCH - 1, aB, aA, 2);

#pragma unroll
    for (int t = 0; t < GT; ++t) {
#pragma unroll
      for (int r = 0; r < 4; ++r) {
        int m = (tb + t) * 16 + kq * 4 + r;
        if (m < ne) {
          OUTS[(size_t)(base + m) * H_ + h0 + col] = acc[t][r];
        }
      }
    }
  }
}

// ---------------- Weighted combine ----------------
__global__ __launch_bounds__(256) void combine_kernel(
    const float* __restrict__ OUTS, const float* __restrict__ topk_w,
    const int* __restrict__ slot2g, float* __restrict__ out) {
  int m = blockIdx.x;
  float w[K_]; int g[K_];
#pragma unroll
  for (int k = 0; k < K_; ++k) { w[k] = topk_w[m * K_ + k]; g[k] = slot2g[m * K_ + k]; }
  for (int h = threadIdx.x; h < H_; h += 256) {
    float s = 0.f;
#pragma unroll
    for (int k = 0; k < K_; ++k) s = fmaf(w[k], OUTS[(size_t)g[k] * H_ + h], s);
    out[(size_t)m * H_ + h] = s;
  }
}

extern "C" void kernel_launch(void* const* d_in, const int* in_sizes, int n_in,
                              void* d_out, int out_size, void* d_ws, size_t ws_size,
                              hipStream_t stream) {
  const float* x   = (const float*)d_in[0];
  const float* gw  = (const float*)d_in[1];
  const float* w13 = (const float*)d_in[2];
  const float* w2  = (const float*)d_in[3];
  float* out = (float*)d_out;

  const int M = in_sizes[0] / H_;   // 512
  const int MK = M * K_;            // 4096

  char* ws = (char*)d_ws;
  size_t o = 0;
  auto alloc = [&](size_t bytes) { size_t r = o; o = (o + bytes + 255) & ~(size_t)255; return r; };
  int*   topk_id  = (int*)(ws + alloc((size_t)MK * 4));
  float* topk_w   = (float*)(ws + alloc((size_t)MK * 4));
  int*   cnt      = (int*)(ws + alloc(E_ * 4));
  int*   off      = (int*)(ws + alloc((E_ + 1) * 4));
  int*   perEx    = (int*)(ws + alloc((size_t)E_ * M * 4));
  int*   entry_mk = (int*)(ws + alloc((size_t)MK * 4));
  int*   slot2g   = (int*)(ws + alloc((size_t)MK * 4));
  __hip_bfloat16* xb  = (__hip_bfloat16*)(ws + alloc((size_t)M * H_ * 2));
  __hip_bfloat16* ACT = (__hip_bfloat16*)(ws + alloc((size_t)MK * I_ * 2));
  float* OUTS     = (float*)(ws + alloc((size_t)MK * H_ * 4));
  (void)ws_size; (void)n_in; (void)out_size;

  router_kernel<<<M, 256, 0, stream>>>(x, gw, topk_id, topk_w, xb, cnt);
  scatter_kernel<<<(MK + 255) / 256, 256, 0, stream>>>(topk_id, cnt, perEx, MK, M);
  scan_kernel<<<1, 64, 0, stream>>>(cnt, off);
  compact_kernel<<<E_, 256, 0, stream>>>(cnt, off, perEx, entry_mk, slot2g, M);
  gateup_mfma<<<dim3(I_ / 64, E_), 256, 0, stream>>>(xb, w13, cnt, off, entry_mk, ACT);
  down_mfma<<<dim3(H_ / 64, E_), 256, 0, stream>>>(ACT, w2, cnt, off, OUTS);
  combine_kernel<<<M, 256, 0, stream>>>(OUTS, topk_w, slot2g, out);
}

// Round 8
// 427.652 us; speedup vs baseline: 4.2045x; 1.0471x over previous
//
#include <hip/hip_runtime.h>
#include <hip/hip_bf16.h>

#define H_ 2048
#define E_ 64
#define I_ 768
#define K_ 8
#define GT 6          // gateup token tiles per pass (96 tokens)
#define GTD 5         // down token tiles per pass (80 tokens)

typedef __attribute__((ext_vector_type(8))) __bf16 bf16x8;
typedef __attribute__((ext_vector_type(4))) float f32x4;

__device__ inline unsigned short f2bfbits(float f) {
  unsigned u = __float_as_uint(f);
  u = (u + 0x7fffu + ((u >> 16) & 1u)) >> 16;   // RNE
  return (unsigned short)u;
}
__device__ inline f32x4 mfma16(bf16x8 a, bf16x8 b, f32x4 c) {
  return __builtin_amdgcn_mfma_f32_16x16x32_bf16(a, b, c, 0, 0, 0);
}
__device__ inline bf16x8 packv(f32x4 a, f32x4 b) {
  union { unsigned u[4]; bf16x8 v; } r;
  asm("v_cvt_pk_bf16_f32 %0, %1, %2" : "=v"(r.u[0]) : "v"(a[0]), "v"(a[1]));
  asm("v_cvt_pk_bf16_f32 %0, %1, %2" : "=v"(r.u[1]) : "v"(a[2]), "v"(a[3]));
  asm("v_cvt_pk_bf16_f32 %0, %1, %2" : "=v"(r.u[2]) : "v"(b[0]), "v"(b[1]));
  asm("v_cvt_pk_bf16_f32 %0, %1, %2" : "=v"(r.u[3]) : "v"(b[2]), "v"(b[3]));
  return r.v;
}
__device__ inline void dma16(const float* g, float* l) {
  __builtin_amdgcn_global_load_lds(
      (const __attribute__((address_space(1))) float*)g,
      (__attribute__((address_space(3))) float*)l, 16, 0, 0);
}
template <int OFS>
__device__ inline f32x4 dsr(unsigned addr) {
  f32x4 d;
  asm volatile("ds_read_b128 %0, %1 offset:%2" : "=v"(d) : "v"(addr), "n"(OFS));
  return d;
}
#define SB() __builtin_amdgcn_sched_barrier(0)
#define LGKM0() do { asm volatile("s_waitcnt lgkmcnt(0)" ::: "memory"); SB(); } while (0)

// ---------------- Router (fp32-exact) + fused x->bf16 cast + cnt zero --------
__global__ __launch_bounds__(256) void router_kernel(
    const float* __restrict__ x, const float* __restrict__ gw,
    int* __restrict__ topk_id, float* __restrict__ topk_w,
    __hip_bfloat16* __restrict__ xb, int* __restrict__ cnt) {
  __shared__ float xs[H_];
  __shared__ float probs[E_];
  int m = blockIdx.x;
  if (m == 0 && threadIdx.x < E_) cnt[threadIdx.x] = 0;
  const float* xr = x + (size_t)m * H_;
  for (int i = threadIdx.x; i < H_; i += 256) xs[i] = xr[i];
  __syncthreads();
  unsigned short* xbr = reinterpret_cast<unsigned short*>(xb) + (size_t)m * H_;
  for (int i = threadIdx.x; i < H_; i += 256) xbr[i] = f2bfbits(xs[i]);
  int e = threadIdx.x >> 2, part = threadIdx.x & 3;
  const float* gr = gw + (size_t)e * H_ + part * (H_ / 4);
  const float* xx = xs + part * (H_ / 4);
  float s = 0.f;
#pragma unroll 8
  for (int i = 0; i < H_ / 4; ++i) s = fmaf(xx[i], gr[i], s);
  s += __shfl_xor(s, 1);
  s += __shfl_xor(s, 2);
  if (part == 0) probs[e] = s;
  __syncthreads();
  if (threadIdx.x == 0) {
    float mx = -1e30f;
    for (int i = 0; i < E_; ++i) mx = fmaxf(mx, probs[i]);
    float sum = 0.f;
    for (int i = 0; i < E_; ++i) { float p = expf(probs[i] - mx); probs[i] = p; sum += p; }
    float inv = 1.f / sum;
    for (int i = 0; i < E_; ++i) probs[i] *= inv;
    float bw[K_]; int bi[K_]; float wsum = 0.f;
#pragma unroll
    for (int k = 0; k < K_; ++k) {
      float best = -1.f; int b = 0;
      for (int i = 0; i < E_; ++i) if (probs[i] > best) { best = probs[i]; b = i; }
      bw[k] = best; bi[k] = b; wsum += best; probs[b] = -2.f;
    }
    float winv = 1.f / wsum;
#pragma unroll
    for (int k = 0; k < K_; ++k) {
      topk_id[m * K_ + k] = bi[k];
      topk_w[m * K_ + k] = bw[k] * winv;
    }
  }
}

// ---------------- Expert list build ----------------
__global__ void scatter_kernel(const int* __restrict__ topk_id, int* cnt,
                               int* perEx, int MK, int M) {
  int idx = blockIdx.x * 256 + threadIdx.x;
  if (idx >= MK) return;
  int e = topk_id[idx];
  int pos = atomicAdd(cnt + e, 1);
  perEx[e * M + pos] = idx;  // idx == m*K_+k
}

__global__ void scan_kernel(const int* cnt, int* off) {
  if (threadIdx.x == 0) {
    int a = 0;
    for (int e = 0; e < E_; ++e) { off[e] = a; a += cnt[e]; }
    off[E_] = a;
  }
}

__global__ void compact_kernel(const int* __restrict__ cnt, const int* __restrict__ off,
                               const int* __restrict__ perEx,
                               int* __restrict__ entry_mk, int* __restrict__ slot2g, int M) {
  int e = blockIdx.x; int n = cnt[e]; int b = off[e];
  for (int p = threadIdx.x; p < n; p += 256) {
    int mk = perEx[e * M + p];
    entry_mk[b + p] = mk;
    slot2g[mk] = b + p;
  }
}

// ---------------- Gate/Up MFMA GEMM + SiLU -> ACT (bf16) ----------------
// Block-coop 64KB weight stages (128 rows x 512B), 2x dbuf, counted vmcnt.
// 512B-contiguous per-row DMA granule (lanes 0-31 row 2q, 32-63 row 2q+1).
__global__ __launch_bounds__(256, 1) void gateup_mfma(
    const __hip_bfloat16* __restrict__ xb, const float* __restrict__ w13,
    const int* __restrict__ cnt, const int* __restrict__ off,
    const int* __restrict__ entry_mk, __hip_bfloat16* __restrict__ ACT) {
  __shared__ __align__(16) float lds[2][16384];   // 2 x 64KB
  const int NST = 16;                              // H/128
  int e = blockIdx.y;
  int ne = cnt[e];
  if (ne == 0) return;
  int base = off[e];
  int wv = threadIdx.x >> 6, lane = threadIdx.x & 63;
  int i0 = blockIdx.x * 64;
  int col = lane & 15, kq = lane >> 4;
  int half = lane >> 5, p = lane & 31;
  const float* w13e = w13 + (size_t)e * (2 * I_) * H_;
  int st0 = (blockIdx.x * 7 + blockIdx.y * 3) & (NST - 1);

  // DMA addressing: wave wv stages local rows [32wv, 32wv+32) (0-63 gate, 64-127 up)
  int rowC = (wv < 2) ? (i0 + 32 * wv + half) : (I_ + i0 + 32 * wv - 64 + half);
  const float* wbase = w13e + (size_t)rowC * H_;
  int xo[4];
#pragma unroll
  for (int j = 0; j < 4; ++j) xo[j] = (p ^ ((j << 1) | half)) * 4;

  auto issueD = [&](int s, int b) {
    int cs = s + st0; if (cs >= NST) cs -= NST;
    const float* bs = wbase + cs * 128;
#pragma unroll
    for (int q = 0; q < 16; ++q)
      dma16(bs + (size_t)(2 * q) * H_ + xo[q & 3], &lds[b][(16 * wv + q) * 256]);
  };

  // read addressing (local row = 16wv+col for gate; +64 for up at +32768B)
  unsigned laneOfs = (unsigned)((8 * wv + (col >> 1)) * 1024 + (col & 1) * 512 +
                                (((kq * 2) ^ (col & 7)) * 16));
  unsigned ldsBase = (unsigned)(size_t)(&lds[0][0]);
  int icol = i0 + 16 * wv + col;

  int ntile = (ne + 15) >> 4;
  for (int tb = 0; tb < ntile; tb += GT) {
    const __hip_bfloat16* arow0[GT];
#pragma unroll
    for (int t = 0; t < GT; ++t) {
      int pt = (tb + t) * 16 + col;
      int pc = pt < ne ? pt : ne - 1;
      int tok = entry_mk[base + pc] >> 3;
      arow0[t] = xb + (size_t)tok * H_ + kq * 8;
    }
    f32x4 accg[GT], accu[GT];
#pragma unroll
    for (int t = 0; t < GT; ++t) {
      accg[t] = (f32x4){0.f, 0.f, 0.f, 0.f};
      accu[t] = (f32x4){0.f, 0.f, 0.f, 0.f};
    }
    bf16x8 aS0[GT], aS1[GT], aS2[GT], aS3[GT];
    auto loadA = [&](bf16x8 (&dst)[GT], int kf) {
#pragma unroll
      for (int t = 0; t < GT; ++t)
        dst[t] = *reinterpret_cast<const bf16x8*>(arow0[t] + kf);
    };
    // prologue: D(0)[16], A(stage0)[24], D(1)[16]
    issueD(0, 0); SB();
    { int k0 = st0 * 128;
      loadA(aS0, k0); loadA(aS1, k0 + 32); loadA(aS2, k0 + 64); loadA(aS3, k0 + 96); }
    SB();
    issueD(1, 1); SB();

#define GJ(JOFS, AC)                                                     \
    {                                                                    \
      f32x4 g0 = dsr<(JOFS)>(a0), g1 = dsr<(JOFS)>(a1);                  \
      f32x4 u0 = dsr<(JOFS) + 32768>(a0), u1 = dsr<(JOFS) + 32768>(a1);  \
      LGKM0();                                                           \
      bf16x8 bg = packv(g0, g1), bu = packv(u0, u1);                     \
      _Pragma("unroll")                                                  \
      for (int t = 0; t < GT; ++t) {                                     \
        accg[t] = mfma16(AC[t], bg, accg[t]);                            \
        accu[t] = mfma16(AC[t], bu, accu[t]);                            \
      }                                                                  \
    }

    for (int s = 0; s < NST; ++s) {
      // retire D(s)+A(s,0); keep A(s,1..3)[18] + D(s+1)[16] in flight
      if (s < NST - 1) { asm volatile("s_waitcnt vmcnt(34)" ::: "memory"); }
      else             { asm volatile("s_waitcnt vmcnt(18)" ::: "memory"); }
      SB();
      __builtin_amdgcn_s_barrier();
      SB();
      unsigned a0 = ldsBase + (unsigned)((s & 1) * 65536) + laneOfs;
      unsigned a1 = a0 ^ 16u;
      GJ(0, aS0)
      GJ(128, aS1)
      GJ(256, aS2)
      GJ(384, aS3)
      if (s < NST - 1) {          // A(s+1,*) BEFORE D(s+2): keeps FIFO decoupled
        int cn = s + 1 + st0; if (cn >= NST) cn -= NST;
        int kn = cn * 128;
        loadA(aS0, kn); loadA(aS1, kn + 32); loadA(aS2, kn + 64); loadA(aS3, kn + 96);
      }
      SB();
      __builtin_amdgcn_s_barrier();
      SB();
      if (s + 2 < NST) { issueD(s + 2, s & 1); SB(); }
    }
#undef GJ

    // epilogue: act = silu(g)*u -> bf16
#pragma unroll
    for (int t = 0; t < GT; ++t) {
#pragma unroll
      for (int r = 0; r < 4; ++r) {
        int m = (tb + t) * 16 + kq * 4 + r;
        if (m < ne) {
          float gv = accg[t][r], uv = accu[t][r];
          float act = gv / (1.f + __expf(-gv)) * uv;
          reinterpret_cast<unsigned short*>(ACT)[(size_t)(base + m) * I_ + icol] =
              f2bfbits(act);
        }
      }
    }
  }
}

// ---------------- Down MFMA GEMM -> OUTS (fp32) ----------------
__global__ __launch_bounds__(256, 2) void down_mfma(
    const __hip_bfloat16* __restrict__ ACT, const float* __restrict__ w2,
    const int* __restrict__ cnt, const int* __restrict__ off,
    float* __restrict__ OUTS) {
  __shared__ __align__(16) float lds[2][8192];    // 2 x 32KB
  const int NST = 6;                               // I/128
  int e = blockIdx.y;
  int ne = cnt[e];
  if (ne == 0) return;
  int base = off[e];
  int wv = threadIdx.x >> 6, lane = threadIdx.x & 63;
  int h0 = blockIdx.x * 64;
  int col = lane & 15, kq = lane >> 4;
  int half = lane >> 5, p = lane & 31;
  const float* w2e = w2 + (size_t)e * H_ * I_;
  int st0 = (int)((unsigned)(blockIdx.x + blockIdx.y * 5) % (unsigned)NST);

  const float* wbase = w2e + (size_t)(h0 + 16 * wv + half) * I_;
  int xo[4];
#pragma unroll
  for (int j = 0; j < 4; ++j) xo[j] = (p ^ ((j << 1) | half)) * 4;

  auto issueD = [&](int s, int b) {
    int cs = s + st0; if (cs >= NST) cs -= NST;
    const float* bs = wbase + cs * 128;
#pragma unroll
    for (int q = 0; q < 8; ++q)
      dma16(bs + (size_t)(2 * q) * I_ + xo[q & 3], &lds[b][(8 * wv + q) * 256]);
  };

  unsigned laneOfs = (unsigned)((8 * wv + (col >> 1)) * 1024 + (col & 1) * 512 +
                                (((kq * 2) ^ (col & 7)) * 16));
  unsigned ldsBase = (unsigned)(size_t)(&lds[0][0]);
  int hcol = h0 + 16 * wv + col;

  int ntile = (ne + 15) >> 4;
  for (int tb = 0; tb < ntile; tb += GTD) {
    const __hip_bfloat16* arow0[GTD];
#pragma unroll
    for (int t = 0; t < GTD; ++t) {
      int pt = (tb + t) * 16 + col;
      int pc = pt < ne ? pt : ne - 1;
      arow0[t] = ACT + (size_t)(base + pc) * I_ + kq * 8;
    }
    f32x4 acc[GTD];
#pragma unroll
    for (int t = 0; t < GTD; ++t) acc[t] = (f32x4){0.f, 0.f, 0.f, 0.f};
    bf16x8 aS0[GTD], aS1[GTD], aS2[GTD], aS3[GTD];
    auto loadA = [&](bf16x8 (&dst)[GTD], int kf) {
#pragma unroll
      for (int t = 0; t < GTD; ++t)
        dst[t] = *reinterpret_cast<const bf16x8*>(arow0[t] + kf);
    };
    issueD(0, 0); SB();
    { int k0 = st0 * 128;
      loadA(aS0, k0); loadA(aS1, k0 + 32); loadA(aS2, k0 + 64); loadA(aS3, k0 + 96); }
    SB();
    issueD(1, 1); SB();

#define DJ(JOFS, AC)                                                     \
    {                                                                    \
      f32x4 w0 = dsr<(JOFS)>(a0), w1 = dsr<(JOFS)>(a1);                  \
      LGKM0();                                                           \
      bf16x8 bw = packv(w0, w1);                                         \
      _Pragma("unroll")                                                  \
      for (int t = 0; t < GTD; ++t) acc[t] = mfma16(AC[t], bw, acc[t]);  \
    }

    for (int s = 0; s < NST; ++s) {
      // retire D(s)+A(s,0); keep A(s,1..3)[15] + D(s+1)[8]
      if (s < NST - 1) { asm volatile("s_waitcnt vmcnt(23)" ::: "memory"); }
      else             { asm volatile("s_waitcnt vmcnt(15)" ::: "memory"); }
      SB();
      __builtin_amdgcn_s_barrier();
      SB();
      unsigned a0 = ldsBase + (unsigned)((s & 1) * 32768) + laneOfs;
      unsigned a1 = a0 ^ 16u;
      DJ(0, aS0)
      DJ(128, aS1)
      DJ(256, aS2)
      DJ(384, aS3)
      if (s < NST - 1) {
        int cn = s + 1 + st0; if (cn >= NST) cn -= NST;
        int kn = cn * 128;
        loadA(aS0, kn); loadA(aS1, kn + 32); loadA(aS2, kn + 64); loadA(aS3, kn + 96);
      }
      SB();
      __builtin_amdgcn_s_barrier();
      SB();
      if (s + 2 < NST) { issueD(s + 2, s & 1); SB(); }
    }
#undef DJ

#pragma unroll
    for (int t = 0; t < GTD; ++t) {
#pragma unroll
      for (int r = 0; r < 4; ++r) {
        int m = (tb + t) * 16 + kq * 4 + r;
        if (m < ne) {
          OUTS[(size_t)(base + m) * H_ + hcol] = acc[t][r];
        }
      }
    }
  }
}

// ---------------- Weighted combine ----------------
__global__ __launch_bounds__(256) void combine_kernel(
    const float* __restrict__ OUTS, const float* __restrict__ topk_w,
    const int* __restrict__ slot2g, float* __restrict__ out) {
  int m = blockIdx.x;
  float w[K_]; int g[K_];
#pragma unroll
  for (int k = 0; k < K_; ++k) { w[k] = topk_w[m * K_ + k]; g[k] = slot2g[m * K_ + k]; }
  for (int h = threadIdx.x; h < H_; h += 256) {
    float s = 0.f;
#pragma unroll
    for (int k = 0; k < K_; ++k) s = fmaf(w[k], OUTS[(size_t)g[k] * H_ + h], s);
    out[(size_t)m * H_ + h] = s;
  }
}

extern "C" void kernel_launch(void* const* d_in, const int* in_sizes, int n_in,
                              void* d_out, int out_size, void* d_ws, size_t ws_size,
                              hipStream_t stream) {
  const float* x   = (const float*)d_in[0];
  const float* gw  = (const float*)d_in[1];
  const float* w13 = (const float*)d_in[2];
  const float* w2  = (const float*)d_in[3];
  float* out = (float*)d_out;

  const int M = in_sizes[0] / H_;   // 512
  const int MK = M * K_;            // 4096

  char* ws = (char*)d_ws;
  size_t o = 0;
  auto alloc = [&](size_t bytes) { size_t r = o; o = (o + bytes + 255) & ~(size_t)255; return r; };
  int*   topk_id  = (int*)(ws + alloc((size_t)MK * 4));
  float* topk_w   = (float*)(ws + alloc((size_t)MK * 4));
  int*   cnt      = (int*)(ws + alloc(E_ * 4));
  int*   off      = (int*)(ws + alloc((E_ + 1) * 4));
  int*   perEx    = (int*)(ws + alloc((size_t)E_ * M * 4));
  int*   entry_mk = (int*)(ws + alloc((size_t)MK * 4));
  int*   slot2g   = (int*)(ws + alloc((size_t)MK * 4));
  __hip_bfloat16* xb  = (__hip_bfloat16*)(ws + alloc((size_t)M * H_ * 2));
  __hip_bfloat16* ACT = (__hip_bfloat16*)(ws + alloc((size_t)MK * I_ * 2));
  float* OUTS     = (float*)(ws + alloc((size_t)MK * H_ * 4));
  (void)ws_size; (void)n_in; (void)out_size;

  router_kernel<<<M, 256, 0, stream>>>(x, gw, topk_id, topk_w, xb, cnt);
  scatter_kernel<<<(MK + 255) / 256, 256, 0, stream>>>(topk_id, cnt, perEx, MK, M);
  scan_kernel<<<1, 64, 0, stream>>>(cnt, off);
  compact_kernel<<<E_, 256, 0, stream>>>(cnt, off, perEx, entry_mk, slot2g, M);
  gateup_mfma<<<dim3(I_ / 64, E_), 256, 0, stream>>>(xb, w13, cnt, off, entry_mk, ACT);
  down_mfma<<<dim3(H_ / 64, E_), 256, 0, stream>>>(ACT, w2, cnt, off, OUTS);
  combine_kernel<<<M, 256, 0, stream>>>(OUTS, topk_w, slot2g, out);
}